// Round 3
// baseline (1206.707 us; speedup 1.0000x reference)
//
#include <hip/hip_runtime.h>

// SharedVectorQuantizer forward for MI355X (gfx950).
// x: [M=65536, D=128] f32, codebook: [K=4096, D=128] f32.
// d_out layout (float32): tokens[M] (as float values) | quantized[M*D] | vq_loss[1]
//
// Matches the harness's numpy-fp32 reference bit-semantics:
//   d2 = fl32( fl32( t1 - 2*t2 ) + t3 ),  argmin (first occurrence)
//   t1 = np.sum(x*x, -1)  (pairwise, SIMD-path dependent -> T1_VARIANT)
//   t2 = sgemm fp32: sequential-K fma chain
//   t3 = np.sum(cb*cb, -1)
//
// ws layout: tok_i[M]*4 | t3[K]*4 | partials[8192]*4

#define D_ 128
#define TM 64
#define TK 64
// 0 = AVX-512 npyv pairwise (8 x 16-lane acc + _mm512_reduce_add_ps tree)
// 1 = scalar 8-accumulator numpy path
// 2 = AVX2 npyv pairwise (8 x 8-lane acc + hadd tree)
#define T1_VARIANT 0

__device__ __forceinline__ float4 f4add(float4 a, float4 b) {
  return make_float4(a.x + b.x, a.y + b.y, a.z + b.z, a.w + b.w);
}
__device__ __forceinline__ float4 f4sq(float4 v) {
  return make_float4(v.x * v.x, v.y * v.y, v.z * v.z, v.w * v.w);
}

// numpy fp32 sum of squares of a 128-float contiguous row (r = 32 float4s)
__device__ __forceinline__ float np_sumsq_row(const float4* __restrict__ r) {
#if T1_VARIANT == 0
  // element e = 16j + l ; l = 4a+b -> float4 index 4j+a, comp b
  float4 W[4];
#pragma unroll
  for (int a = 0; a < 4; ++a) {
    float4 c0 = f4sq(r[0 * 4 + a]), c1 = f4sq(r[1 * 4 + a]);
    float4 c2 = f4sq(r[2 * 4 + a]), c3 = f4sq(r[3 * 4 + a]);
    float4 c4 = f4sq(r[4 * 4 + a]), c5 = f4sq(r[5 * 4 + a]);
    float4 c6 = f4sq(r[6 * 4 + a]), c7 = f4sq(r[7 * 4 + a]);
    W[a] = f4add(f4add(f4add(c0, c1), f4add(c2, c3)),
                 f4add(f4add(c4, c5), f4add(c6, c7)));
  }
  // _mm512_reduce_add_ps tree: (l,l+8) -> (l,l+4) -> (l,l+2) -> (l,l+1)
  float4 U0 = f4add(W[0], W[2]);
  float4 U1 = f4add(W[1], W[3]);
  float4 T = f4add(U0, U1);
  float s0 = T.x + T.z, s1 = T.y + T.w;
  return s0 + s1;
#elif T1_VARIANT == 1
  // r[j] = a[j]; for i=1..15: r[j] += a[8i+j]; tree combine
  float4 r0 = f4sq(r[0]), r1 = f4sq(r[1]);
#pragma unroll
  for (int i = 1; i < 16; ++i) {
    r0 = f4add(r0, f4sq(r[2 * i]));
    r1 = f4add(r1, f4sq(r[2 * i + 1]));
  }
  return ((r0.x + r0.y) + (r0.z + r0.w)) + ((r1.x + r1.y) + (r1.z + r1.w));
#else
  // AVX2: R[j][l] = q[8j+l] + q[64+8j+l]; tree over j; hadd-tree over 8 lanes
  float4 RA[8], RB[8];
#pragma unroll
  for (int j = 0; j < 8; ++j) {
    RA[j] = f4add(f4sq(r[2 * j]),     f4sq(r[16 + 2 * j]));
    RB[j] = f4add(f4sq(r[2 * j + 1]), f4sq(r[16 + 2 * j + 1]));
  }
  float4 WA = f4add(f4add(f4add(RA[0], RA[1]), f4add(RA[2], RA[3])),
                    f4add(f4add(RA[4], RA[5]), f4add(RA[6], RA[7])));
  float4 WB = f4add(f4add(f4add(RB[0], RB[1]), f4add(RB[2], RB[3])),
                    f4add(f4add(RB[4], RB[5]), f4add(RB[6], RB[7])));
  return ((WA.x + WA.y) + (WA.z + WA.w)) + ((WB.x + WB.y) + (WB.z + WB.w));
#endif
}

__global__ __launch_bounds__(256, 2)
void k_t3(const float* __restrict__ cb, float* __restrict__ t3, int K) {
  int k = blockIdx.x * blockDim.x + threadIdx.x;
  if (k >= K) return;
  t3[k] = np_sumsq_row((const float4*)(cb + (size_t)k * D_));
}

__global__ __launch_bounds__(256, 2)
void k_argmin(const float* __restrict__ x, const float* __restrict__ cb,
              const float* __restrict__ t3, float* __restrict__ tok_f,
              int* __restrict__ tok_i, int K) {
  __shared__ float xs[TM * D_];   // linear [row][d]
  __shared__ float es[TK * D_];   // XOR-swizzled: float4 col (d4 ^ (c&7))
  const int tid = threadIdx.x;
  const int tx = tid & 15;        // code group
  const int ty = tid >> 4;        // row group
  const size_t row0 = (size_t)blockIdx.x * TM;

  // stage x tile: 64 rows x 128 f32 = 32 KB, linear copy
  {
    const float4* src = (const float4*)(x + row0 * D_);
    float4* dst = (float4*)xs;
#pragma unroll
    for (int it = 0; it < 8; ++it) dst[tid + it * 256] = src[tid + it * 256];
  }
  __syncthreads();

  const float4* xs4 = (const float4*)xs;
  const float4* es4 = (const float4*)es;

  // per-row numpy t1 (all 16 threads of a row group compute it redundantly)
  float t1v[4];
#pragma unroll
  for (int i = 0; i < 4; ++i)
    t1v[i] = np_sumsq_row(xs4 + (((size_t)(i * 16 + ty)) << 5));

  float m1[4]; int i1[4];
#pragma unroll
  for (int i = 0; i < 4; ++i) { m1[i] = 3.4e38f; i1[i] = 0; }

  const int me = tx & 7;

  for (int c0 = 0; c0 < K; c0 += TK) {
    __syncthreads();   // previous chunk's reads done before overwrite
    {
      const float4* src = (const float4*)(cb + (size_t)c0 * D_);
#pragma unroll
      for (int it = 0; it < 8; ++it) {
        int f4 = tid + it * 256;        // 0..2047 within chunk
        float4 v = src[f4];
        int c = f4 >> 5;                // code within chunk
        int d4 = f4 & 31;
        ((float4*)es)[(c << 5) | (d4 ^ (c & 7))] = v;
      }
    }
    __syncthreads();

    float acc[4][4];
#pragma unroll
    for (int i = 0; i < 4; ++i)
#pragma unroll
      for (int j = 0; j < 4; ++j) acc[i][j] = 0.f;

    // strictly ordered fp32 fma chain over k = 0..127 (sgemm emulation)
#pragma unroll 8
    for (int d4 = 0; d4 < 32; ++d4) {
      float4 xv[4], ev[4];
#pragma unroll
      for (int i = 0; i < 4; ++i)
        xv[i] = xs4[((i * 16 + ty) << 5) | d4];
      const int ec = d4 ^ me;
#pragma unroll
      for (int j = 0; j < 4; ++j)
        ev[j] = es4[((j * 16 + tx) << 5) | ec];
#pragma unroll
      for (int i = 0; i < 4; ++i)
#pragma unroll
        for (int j = 0; j < 4; ++j) {
          float a = acc[i][j];
          a = __builtin_fmaf(xv[i].x, ev[j].x, a);
          a = __builtin_fmaf(xv[i].y, ev[j].y, a);
          a = __builtin_fmaf(xv[i].z, ev[j].z, a);
          a = __builtin_fmaf(xv[i].w, ev[j].w, a);
          acc[i][j] = a;
        }
    }

    // numpy-exact score: fl( fl(t1 - 2*t2) + t3 )
#pragma unroll
    for (int j = 0; j < 4; ++j) {
      int c = c0 + j * 16 + tx;
      float t3v = t3[c];
#pragma unroll
      for (int i = 0; i < 4; ++i) {
        float r1 = __builtin_fmaf(-2.f, acc[i][j], t1v[i]);  // == fl(t1-2*acc)
        float s = r1 + t3v;
        if (s < m1[i]) { m1[i] = s; i1[i] = c; }   // strict <: keeps lowest idx
      }
    }
  }

  // argmin merge across the 16 tx-lanes sharing each row (lowest idx on ties)
#pragma unroll
  for (int i = 0; i < 4; ++i) {
    float a1 = m1[i]; int ai = i1[i];
#pragma unroll
    for (int off = 1; off < 16; off <<= 1) {
      float b1 = __shfl_xor(a1, off, 64);
      int   bi = __shfl_xor(ai, off, 64);
      bool take = (b1 < a1) || (b1 == a1 && bi < ai);
      a1 = take ? b1 : a1;
      ai = take ? bi : ai;
    }
    if (tx == 0) {
      size_t r = row0 + (size_t)(i * 16 + ty);
      tok_f[r] = (float)ai;
      tok_i[r] = ai;
    }
  }
}

// gather quantized rows + per-block partial MSE sums (no atomics)
__global__ __launch_bounds__(256, 2)
void k_gather(const float* __restrict__ x, const float* __restrict__ cb,
              const int* __restrict__ tok_i, float* __restrict__ outq,
              float* __restrict__ partial) {
  int idx = blockIdx.x * 256 + threadIdx.x;    // float4 index, 32 per row
  int row = idx >> 5;
  int d4  = idx & 31;
  int t = tok_i[row];
  float4 q  = ((const float4*)(cb + (size_t)t * D_))[d4];
  float4 xv = ((const float4*)x)[idx];
  ((float4*)outq)[idx] = q;
  float dx = q.x - xv.x, dy = q.y - xv.y, dz = q.z - xv.z, dw = q.w - xv.w;
  float s = dx * dx + dy * dy + dz * dz + dw * dw;
#pragma unroll
  for (int off = 1; off < 64; off <<= 1) s += __shfl_xor(s, off, 64);
  __shared__ float red[4];
  int lane = threadIdx.x & 63, w = threadIdx.x >> 6;
  if (lane == 0) red[w] = s;
  __syncthreads();
  if (threadIdx.x == 0)
    partial[blockIdx.x] = red[0] + red[1] + red[2] + red[3];
}

__global__ __launch_bounds__(256, 1)
void k_loss(const float* __restrict__ partial, int n, float* __restrict__ out_loss,
            float scale) {
  float s = 0.f;
  for (int i = threadIdx.x; i < n; i += 256) s += partial[i];
#pragma unroll
  for (int off = 1; off < 64; off <<= 1) s += __shfl_xor(s, off, 64);
  __shared__ float red[4];
  int lane = threadIdx.x & 63, w = threadIdx.x >> 6;
  if (lane == 0) red[w] = s;
  __syncthreads();
  if (threadIdx.x == 0)
    out_loss[0] = (red[0] + red[1] + red[2] + red[3]) * scale;
}

extern "C" void kernel_launch(void* const* d_in, const int* in_sizes, int n_in,
                              void* d_out, int out_size, void* d_ws, size_t ws_size,
                              hipStream_t stream) {
  const float* x  = (const float*)d_in[0];
  const float* cb = (const float*)d_in[1];
  const int M = in_sizes[0] / D_;   // 65536
  const int K = in_sizes[1] / D_;   // 4096

  float* out_tok  = (float*)d_out;                       // tokens as float values
  float* out_q    = (float*)d_out + M;                   // quantized_ste
  float* out_loss = (float*)d_out + M + (size_t)M * D_;  // vq_loss scalar

  char* ws = (char*)d_ws;
  int*   tok_i = (int*)ws;                                   // M ints
  float* t3    = (float*)(ws + (size_t)M * 4);               // K floats
  float* part  = (float*)(ws + (size_t)M * 4 + (size_t)K * 4);

  const int gB = (M * (D_ / 4)) / 256;   // 8192 blocks for gather

  k_t3    <<<(K + 255) / 256, 256, 0, stream>>>(cb, t3, K);
  k_argmin<<<M / TM,          256, 0, stream>>>(x, cb, t3, out_tok, tok_i, K);
  k_gather<<<gB,              256, 0, stream>>>(x, cb, tok_i, out_q, part);
  k_loss  <<<1,               256, 0, stream>>>(part, gB, out_loss,
                                                1.5f / (float)((size_t)M * D_));
}

// Round 4
// 691.311 us; speedup vs baseline: 1.7455x; 1.7455x over previous
//
#include <hip/hip_runtime.h>

// SharedVectorQuantizer forward, MI355X. x:[65536,128]f32 cb:[4096,128]f32
// out: tokens[M] (float) | quantized[M*128] | vq_loss[1]
//
// Pipeline: k_t3 (np ||e||^2 + bf16 split), k_t1 (np ||x||^2), k_prep
// (codebook -> bf16 hi/lo, fragment-linear chunk layout + t3 MFMA slab),
// k_big (bf16-split MFMA approx: per (row, 64-code chunk) max of acc;
// score = -2*acc), k_cand (per row: chunks within delta of best -> pairs),
// k_exact (np-bit-exact fp32 chain rescore of candidate chunks, u64
// atomicMin of (score_bits<<12)|code), k_final, k_gather, k_loss.
//
// Big scratch lives in the quantized-output region (dead before k_gather).

#define D_ 128
#define MROWS 65536
#define KCODES 4096
#define ECAP 2048

// float offsets within out_q scratch region (8388608 floats)
#define OQ_AH    4194304   // 64 chunks * 1152 units * 16B (bf16 hi, +t3 slabs)
#define OQ_AL    4489216   // bf16 lo (padded to 1152 units/chunk)
#define OQ_KEYS  4784128   // u64[65536]
#define OQ_PAIRS 4915200   // int[64*ECAP]
#define OQ_T1    5046272   // f32[65536]
#define OQ_T3    5111808   // f32[4096]
#define OQ_T3HL  5115904   // u32[4096] packed t3h | t3l<<16
#define OQ_CNT   5120000   // int[64]

typedef __attribute__((ext_vector_type(8))) short bf16x8;
typedef __attribute__((ext_vector_type(16))) float f32x16;

__device__ __forceinline__ unsigned short bf16rne(float f) {
  unsigned u = __float_as_uint(f);
  unsigned r = (u + 0x7FFFu + ((u >> 16) & 1u)) >> 16;
  return (unsigned short)r;
}
__device__ __forceinline__ float bf16tof(unsigned short h) {
  return __uint_as_float(((unsigned)h) << 16);
}

__device__ __forceinline__ void gload_lds16(const void* g, void* l) {
  __builtin_amdgcn_global_load_lds(
      (const __attribute__((address_space(1))) unsigned int*)g,
      (__attribute__((address_space(3))) unsigned int*)l, 16, 0, 0);
}

__device__ __forceinline__ float4 f4add(float4 a, float4 b) {
  return make_float4(a.x + b.x, a.y + b.y, a.z + b.z, a.w + b.w);
}
__device__ __forceinline__ float4 f4sq(float4 v) {
  return make_float4(v.x * v.x, v.y * v.y, v.z * v.z, v.w * v.w);
}

// numpy fp32 pairwise sum of squares, AVX-512 npyv path (verified round 3)
__device__ __forceinline__ float np_sumsq_row(const float4* __restrict__ r) {
  float4 W[4];
#pragma unroll
  for (int a = 0; a < 4; ++a) {
    float4 c0 = f4sq(r[0 * 4 + a]), c1 = f4sq(r[1 * 4 + a]);
    float4 c2 = f4sq(r[2 * 4 + a]), c3 = f4sq(r[3 * 4 + a]);
    float4 c4 = f4sq(r[4 * 4 + a]), c5 = f4sq(r[5 * 4 + a]);
    float4 c6 = f4sq(r[6 * 4 + a]), c7 = f4sq(r[7 * 4 + a]);
    W[a] = f4add(f4add(f4add(c0, c1), f4add(c2, c3)),
                 f4add(f4add(c4, c5), f4add(c6, c7)));
  }
  float4 U0 = f4add(W[0], W[2]);
  float4 U1 = f4add(W[1], W[3]);
  float4 T = f4add(U0, U1);
  float s0 = T.x + T.z, s1 = T.y + T.w;
  return s0 + s1;
}

__global__ __launch_bounds__(256, 2)
void k_t3(const float* __restrict__ cb, float* __restrict__ t3,
          unsigned* __restrict__ t3hl) {
  int k = blockIdx.x * 256 + threadIdx.x;
  float s = np_sumsq_row((const float4*)(cb + (size_t)k * D_));
  t3[k] = s;
  unsigned short h = bf16rne(s);
  unsigned short l = bf16rne(s - bf16tof(h));
  t3hl[k] = (unsigned)h | ((unsigned)l << 16);
}

__global__ __launch_bounds__(256, 2)
void k_t1(const float* __restrict__ x, float* __restrict__ t1) {
  int r = blockIdx.x * 256 + threadIdx.x;
  t1[r] = np_sumsq_row((const float4*)(x + (size_t)r * D_));
}

// codebook -> fragment-linear bf16 hi/lo units.
// unit u in [0, 64*1152): ch = u/1152, slab s = (u%1152)>>6, p = u&63.
// s<16: kt=s>>1, ct=s&1: code = ch*64+ct*32+(p&31), k16 = kt*2+(p>>5).
// s>=16: t3 slab (ct=s-16): kg==0 lane: {t3h, t3l, 0...}.
__global__ __launch_bounds__(256, 2)
void k_prep(const float* __restrict__ cb, const unsigned* __restrict__ t3hl,
            float* __restrict__ outq) {
  int u = blockIdx.x * 256 + threadIdx.x;   // < 73728
  int ch = u / 1152, r = u - ch * 1152;
  int s = r >> 6, p = r & 63;
  int kg = p >> 5, nl = p & 31;
  bf16x8 h = 0, l = 0;
  if (s < 16) {
    int kt = s >> 1, ct = s & 1;
    int code = ch * 64 + ct * 32 + nl;
    const float* src = cb + (size_t)code * D_ + (kt * 2 + kg) * 8;
#pragma unroll
    for (int e = 0; e < 8; ++e) {
      float f = src[e];
      unsigned short hs = bf16rne(f);
      unsigned short ls = bf16rne(f - bf16tof(hs));
      h[e] = (short)hs;
      l[e] = (short)ls;
    }
  } else {
    int ct = s - 16;
    int code = ch * 64 + ct * 32 + nl;
    if (kg == 0) {
      unsigned v = t3hl[code];
      h[0] = (short)(v & 0xFFFFu);
      h[1] = (short)(v >> 16);
    }
  }
  *(bf16x8*)((char*)(outq + OQ_AH) + (size_t)u * 16) = h;
  *(bf16x8*)((char*)(outq + OQ_AL) + (size_t)u * 16) = l;
}

// Approx sweep. 512 thr = 8 waves = 4 row-groups x 2 code-halves.
// Wave: 64 rows (x frags in regs) x 64-code chunks from LDS (dbuf).
// acc = xh*eh + xl*eh + xh*el - 0.5*(t3h+t3l); cm[ch][row] = max acc.
__global__ __launch_bounds__(512, 2)
void k_big(const float* __restrict__ x, float* __restrict__ outq) {
  extern __shared__ char lds[];
  const int tid = threadIdx.x;
  const int lane = tid & 63;
  const int wid = tid >> 6;
  const int rg = wid >> 1, cs = wid & 1;
  const int kg = lane >> 5, nl = lane & 31;
  const int row0 = blockIdx.x * 256 + rg * 64;

  const char* AhB = (const char*)(outq + OQ_AH);
  const char* AlB = (const char*)(outq + OQ_AL);
  float* cm = outq;   // [64][65536]

  // x fragments: xh/xl[xt][kt], lane holds row row0+xt*32+nl, k16 = kt*2+kg
  bf16x8 xh[2][8], xl[2][8];
#pragma unroll
  for (int xt = 0; xt < 2; ++xt)
#pragma unroll
    for (int kt = 0; kt < 8; ++kt) {
      const float* src = x + (size_t)(row0 + xt * 32 + nl) * D_ + (kt * 2 + kg) * 8;
      float f[8];
      *(float4*)(f) = *(const float4*)(src);
      *(float4*)(f + 4) = *(const float4*)(src + 4);
      bf16x8 h, l;
#pragma unroll
      for (int e = 0; e < 8; ++e) {
        unsigned short hs = bf16rne(f[e]);
        float hf = bf16tof(hs);
        unsigned short ls = bf16rne(f[e] - hf);
        h[e] = (short)hs;
        l[e] = (short)ls;
      }
      xh[xt][kt] = h;
      xl[xt][kt] = l;
    }

  // constant B frag for t3 slab: k=128,129 hold -0.5 (bf16 0xBF00)
  bf16x8 bneg = 0;
  if (kg == 0) { bneg[0] = (short)0xBF00; bneg[1] = (short)0xBF00; }

  char* half = lds + cs * 73728;

  // stage chunk c into buffer buf (4 waves of this cs-group, 9 iters)
#define STAGE(c, buf)                                                         \
  {                                                                           \
    const char* sAh = AhB + (size_t)(c) * 18432;                              \
    const char* sAl = AlB + (size_t)(c) * 18432;                              \
    _Pragma("unroll")                                                         \
    for (int it9 = 0; it9 < 9; ++it9) {                                       \
      int ub = it9 * 256 + rg * 64;                                           \
      int uu = ub + lane;                                                     \
      if (ub < 1152) gload_lds16(sAh + (size_t)uu * 16, (buf) + ub * 16);     \
      else gload_lds16(sAl + (size_t)(uu - 1152) * 16,                        \
                       (buf) + 18432 + (ub - 1152) * 16);                     \
    }                                                                         \
  }

  STAGE(cs * 32 + 0, half + 0);
  __syncthreads();

  int b = 0;
  for (int it = 0; it < 32; ++it) {
    char* cur = half + b * 36864;
    if (it < 31) STAGE(cs * 32 + it + 1, half + (b ^ 1) * 36864);

    f32x16 a00 = 0, a01 = 0, a10 = 0, a11 = 0;   // a[ct][xt]
#pragma unroll
    for (int kt = 0; kt < 8; ++kt) {
      bf16x8 eh0 = *(const bf16x8*)(cur + ((kt * 2 + 0) * 64 + lane) * 16);
      bf16x8 eh1 = *(const bf16x8*)(cur + ((kt * 2 + 1) * 64 + lane) * 16);
      bf16x8 el0 = *(const bf16x8*)(cur + 18432 + ((kt * 2 + 0) * 64 + lane) * 16);
      bf16x8 el1 = *(const bf16x8*)(cur + 18432 + ((kt * 2 + 1) * 64 + lane) * 16);
      a00 = __builtin_amdgcn_mfma_f32_32x32x16_bf16(eh0, xh[0][kt], a00, 0, 0, 0);
      a00 = __builtin_amdgcn_mfma_f32_32x32x16_bf16(el0, xh[0][kt], a00, 0, 0, 0);
      a00 = __builtin_amdgcn_mfma_f32_32x32x16_bf16(eh0, xl[0][kt], a00, 0, 0, 0);
      a01 = __builtin_amdgcn_mfma_f32_32x32x16_bf16(eh0, xh[1][kt], a01, 0, 0, 0);
      a01 = __builtin_amdgcn_mfma_f32_32x32x16_bf16(el0, xh[1][kt], a01, 0, 0, 0);
      a01 = __builtin_amdgcn_mfma_f32_32x32x16_bf16(eh0, xl[1][kt], a01, 0, 0, 0);
      a10 = __builtin_amdgcn_mfma_f32_32x32x16_bf16(eh1, xh[0][kt], a10, 0, 0, 0);
      a10 = __builtin_amdgcn_mfma_f32_32x32x16_bf16(el1, xh[0][kt], a10, 0, 0, 0);
      a10 = __builtin_amdgcn_mfma_f32_32x32x16_bf16(eh1, xl[0][kt], a10, 0, 0, 0);
      a11 = __builtin_amdgcn_mfma_f32_32x32x16_bf16(eh1, xh[1][kt], a11, 0, 0, 0);
      a11 = __builtin_amdgcn_mfma_f32_32x32x16_bf16(el1, xh[1][kt], a11, 0, 0, 0);
      a11 = __builtin_amdgcn_mfma_f32_32x32x16_bf16(eh1, xl[1][kt], a11, 0, 0, 0);
    }
    {
      bf16x8 t30 = *(const bf16x8*)(cur + ((16 + 0) * 64 + lane) * 16);
      bf16x8 t31 = *(const bf16x8*)(cur + ((16 + 1) * 64 + lane) * 16);
      a00 = __builtin_amdgcn_mfma_f32_32x32x16_bf16(t30, bneg, a00, 0, 0, 0);
      a01 = __builtin_amdgcn_mfma_f32_32x32x16_bf16(t30, bneg, a01, 0, 0, 0);
      a10 = __builtin_amdgcn_mfma_f32_32x32x16_bf16(t31, bneg, a10, 0, 0, 0);
      a11 = __builtin_amdgcn_mfma_f32_32x32x16_bf16(t31, bneg, a11, 0, 0, 0);
    }

    float m0 = -3.4e38f, m1v = -3.4e38f;
#pragma unroll
    for (int e = 0; e < 16; ++e) {
      m0 = fmaxf(m0, fmaxf(a00[e], a10[e]));
      m1v = fmaxf(m1v, fmaxf(a01[e], a11[e]));
    }
    m0 = fmaxf(m0, __shfl_xor(m0, 32, 64));
    m1v = fmaxf(m1v, __shfl_xor(m1v, 32, 64));
    if (lane < 32) {
      size_t base = (size_t)(cs * 32 + it) * MROWS + row0;
      cm[base + nl] = m0;
      cm[base + 32 + nl] = m1v;
    }
    __syncthreads();
    b ^= 1;
  }
#undef STAGE
}

__global__ __launch_bounds__(256, 2)
void k_cand(const float* __restrict__ cm, int* __restrict__ cnt,
            int* __restrict__ pairs, unsigned long long* __restrict__ keys,
            float dlt) {
  int r = blockIdx.x * 256 + threadIdx.x;
  float A = -3.4e38f;
  for (int ch = 0; ch < 64; ++ch) A = fmaxf(A, cm[(size_t)ch * MROWS + r]);
  keys[r] = ~0ull;
  float thr = A - dlt;
  for (int ch = 0; ch < 64; ++ch) {
    if (cm[(size_t)ch * MROWS + r] >= thr) {
      int s = atomicAdd(cnt + ch, 1);
      if (s < ECAP) pairs[ch * ECAP + s] = r;
    }
  }
}

// np-bit-exact rescore of candidate chunks. Block: chunk ch = bid>>4,
// sub-slice sub = bid&15. Codes staged d4-major with 65-unit pad.
__global__ __launch_bounds__(256, 2)
void k_exact(const float* __restrict__ x, const float* __restrict__ cb,
             const int* __restrict__ cnt, const int* __restrict__ pairs,
             const float* __restrict__ t1, const float* __restrict__ t3,
             unsigned long long* __restrict__ keys) {
  __shared__ float elds[32 * 65 * 4];
  __shared__ float xlds[4][D_];
  int ch = blockIdx.x >> 4, sub = blockIdx.x & 15;
  int tid = threadIdx.x, lane = tid & 63, wid = tid >> 6;
#pragma unroll
  for (int it2 = 0; it2 < 8; ++it2) {
    int u = it2 * 256 + tid;        // 0..2047
    int c = u >> 5, d4 = u & 31;
    float4 v = *(const float4*)(cb + ((size_t)ch * 64 + c) * D_ + d4 * 4);
    *(float4*)(elds + (d4 * 65 + c) * 4) = v;
  }
  float t3v = t3[ch * 64 + lane];
  __syncthreads();
  int n = cnt[ch]; if (n > ECAP) n = ECAP;
  int start = (sub * n) >> 4, end = ((sub + 1) * n) >> 4;
  for (int idx = start + wid; idx < end; idx += 4) {
    int row = pairs[ch * ECAP + idx];
    *(float2*)(&xlds[wid][lane * 2]) = *(const float2*)(x + (size_t)row * D_ + lane * 2);
    asm volatile("s_waitcnt lgkmcnt(0)" ::: "memory");
    float acc = 0.f;
    float t1r = t1[row];
#pragma unroll 8
    for (int d4 = 0; d4 < 32; ++d4) {
      float4 xv = *(const float4*)(&xlds[wid][d4 * 4]);
      float4 ev = *(const float4*)(elds + (d4 * 65 + lane) * 4);
      acc = __builtin_fmaf(xv.x, ev.x, acc);
      acc = __builtin_fmaf(xv.y, ev.y, acc);
      acc = __builtin_fmaf(xv.z, ev.z, acc);
      acc = __builtin_fmaf(xv.w, ev.w, acc);
    }
    float s = __builtin_fmaf(-2.f, acc, t1r) + t3v;
    unsigned u32 = __float_as_uint(s);
    u32 = u32 ^ (unsigned)(((int)u32 >> 31) | 0x80000000);  // monotonic map
    unsigned long long key =
        ((unsigned long long)u32 << 12) | (unsigned)(ch * 64 + lane);
#pragma unroll
    for (int off = 1; off < 64; off <<= 1) {
      unsigned long long o = __shfl_xor(key, off, 64);
      key = o < key ? o : key;
    }
    if (lane == 0) atomicMin(keys + row, key);
  }
}

__global__ __launch_bounds__(256, 2)
void k_final(const unsigned long long* __restrict__ keys,
             float* __restrict__ tok_f, int* __restrict__ tok_i) {
  int r = blockIdx.x * 256 + threadIdx.x;
  int code = (int)(keys[r] & 0xFFFull);
  tok_f[r] = (float)code;
  tok_i[r] = code;
}

__global__ __launch_bounds__(256, 2)
void k_gather(const float* __restrict__ x, const float* __restrict__ cb,
              const int* __restrict__ tok_i, float* __restrict__ outq,
              float* __restrict__ partial) {
  int idx = blockIdx.x * 256 + threadIdx.x;
  int row = idx >> 5;
  int d4 = idx & 31;
  int t = tok_i[row];
  float4 q = ((const float4*)(cb + (size_t)t * D_))[d4];
  float4 xv = ((const float4*)x)[idx];
  ((float4*)outq)[idx] = q;
  float dx = q.x - xv.x, dy = q.y - xv.y, dz = q.z - xv.z, dw = q.w - xv.w;
  float s = dx * dx + dy * dy + dz * dz + dw * dw;
#pragma unroll
  for (int off = 1; off < 64; off <<= 1) s += __shfl_xor(s, off, 64);
  __shared__ float red[4];
  int lane = threadIdx.x & 63, w = threadIdx.x >> 6;
  if (lane == 0) red[w] = s;
  __syncthreads();
  if (threadIdx.x == 0)
    partial[blockIdx.x] = red[0] + red[1] + red[2] + red[3];
}

__global__ __launch_bounds__(256, 1)
void k_loss(const float* __restrict__ partial, int n, float* __restrict__ out_loss,
            float scale) {
  float s = 0.f;
  for (int i = threadIdx.x; i < n; i += 256) s += partial[i];
#pragma unroll
  for (int off = 1; off < 64; off <<= 1) s += __shfl_xor(s, off, 64);
  __shared__ float red[4];
  int lane = threadIdx.x & 63, w = threadIdx.x >> 6;
  if (lane == 0) red[w] = s;
  __syncthreads();
  if (threadIdx.x == 0)
    out_loss[0] = (red[0] + red[1] + red[2] + red[3]) * scale;
}

extern "C" void kernel_launch(void* const* d_in, const int* in_sizes, int n_in,
                              void* d_out, int out_size, void* d_ws, size_t ws_size,
                              hipStream_t stream) {
  const float* x = (const float*)d_in[0];
  const float* cb = (const float*)d_in[1];

  float* out_tok = (float*)d_out;
  float* outq = (float*)d_out + MROWS;
  float* out_loss = (float*)d_out + MROWS + (size_t)MROWS * D_;

  int* tok_i = (int*)d_ws;                          // 256 KB
  float* part = (float*)((char*)d_ws + 262144);     // 32 KB

  float* t3 = outq + OQ_T3;
  float* t1 = outq + OQ_T1;
  unsigned* t3hl = (unsigned*)(outq + OQ_T3HL);
  int* cnt = (int*)(outq + OQ_CNT);
  int* pairs = (int*)(outq + OQ_PAIRS);
  unsigned long long* keys = (unsigned long long*)(outq + OQ_KEYS);

  k_t3<<<KCODES / 256, 256, 0, stream>>>(cb, t3, t3hl);
  k_t1<<<MROWS / 256, 256, 0, stream>>>(x, t1);
  k_prep<<<(64 * 1152) / 256, 256, 0, stream>>>(cb, t3hl, outq);
  k_big<<<MROWS / 256, 512, 147456, stream>>>(x, outq);
  hipMemsetAsync(cnt, 0, 64 * sizeof(int), stream);
  k_cand<<<MROWS / 256, 256, 0, stream>>>(outq, cnt, pairs, keys, 2e-3f);
  k_exact<<<64 * 16, 256, 0, stream>>>(x, cb, cnt, pairs, t1, t3, keys);
  k_final<<<MROWS / 256, 256, 0, stream>>>(keys, out_tok, tok_i);
  const int gB = (MROWS * (D_ / 4)) / 256;
  k_gather<<<gB, 256, 0, stream>>>(x, cb, tok_i, outq, part);
  k_loss<<<1, 256, 0, stream>>>(part, gB, out_loss,
                                1.5f / (float)((size_t)MROWS * D_));
}

// Round 5
// 682.877 us; speedup vs baseline: 1.7671x; 1.0124x over previous
//
#include <hip/hip_runtime.h>

// SharedVectorQuantizer forward, MI355X. x:[65536,128]f32 cb:[4096,128]f32
// out: tokens[M] (float) | quantized[M*128] | vq_loss[1]
//
// Pipeline: k_t3 (np ||e||^2 + bf16 split), k_t1 (np ||x||^2), k_prep
// (codebook -> bf16 hi/lo, fragment-linear chunk layout + t3 MFMA slab),
// k_big (bf16-split MFMA approx: per (row, 64-code chunk) max of acc;
// score = -2*acc), k_cand (per row: chunks within delta of best -> pairs),
// k_exact (np-bit-exact fp32 chain rescore of candidate chunks, u64
// atomicMin of (score_bits<<12)|code), k_final, k_gather, k_loss.
//
// Big scratch lives in the quantized-output region (dead before k_gather).

#define D_ 128
#define MROWS 65536
#define KCODES 4096
#define ECAP 2048

// float offsets within out_q scratch region (8388608 floats)
#define OQ_AH    4194304   // 64 chunks * 1152 units * 16B (bf16 hi, +t3 slabs)
#define OQ_AL    4489216   // bf16 lo (padded to 1152 units/chunk)
#define OQ_KEYS  4784128   // u64[65536]
#define OQ_PAIRS 4915200   // int[64*ECAP]
#define OQ_T1    5046272   // f32[65536]
#define OQ_T3    5111808   // f32[4096]
#define OQ_T3HL  5115904   // u32[4096] packed t3h | t3l<<16
#define OQ_CNT   5120000   // int[64]

typedef __attribute__((ext_vector_type(8))) short bf16x8;
typedef __attribute__((ext_vector_type(16))) float f32x16;

__device__ __forceinline__ unsigned short bf16rne(float f) {
  unsigned u = __float_as_uint(f);
  unsigned r = (u + 0x7FFFu + ((u >> 16) & 1u)) >> 16;
  return (unsigned short)r;
}
__device__ __forceinline__ float bf16tof(unsigned short h) {
  return __uint_as_float(((unsigned)h) << 16);
}

__device__ __forceinline__ void gload_lds16(const void* g, void* l) {
  __builtin_amdgcn_global_load_lds(
      (const __attribute__((address_space(1))) unsigned int*)g,
      (__attribute__((address_space(3))) unsigned int*)l, 16, 0, 0);
}

__device__ __forceinline__ float4 f4add(float4 a, float4 b) {
  return make_float4(a.x + b.x, a.y + b.y, a.z + b.z, a.w + b.w);
}
__device__ __forceinline__ float4 f4sq(float4 v) {
  return make_float4(v.x * v.x, v.y * v.y, v.z * v.z, v.w * v.w);
}

// numpy fp32 pairwise sum of squares, AVX-512 npyv path (verified round 3)
__device__ __forceinline__ float np_sumsq_row(const float4* __restrict__ r) {
  float4 W[4];
#pragma unroll
  for (int a = 0; a < 4; ++a) {
    float4 c0 = f4sq(r[0 * 4 + a]), c1 = f4sq(r[1 * 4 + a]);
    float4 c2 = f4sq(r[2 * 4 + a]), c3 = f4sq(r[3 * 4 + a]);
    float4 c4 = f4sq(r[4 * 4 + a]), c5 = f4sq(r[5 * 4 + a]);
    float4 c6 = f4sq(r[6 * 4 + a]), c7 = f4sq(r[7 * 4 + a]);
    W[a] = f4add(f4add(f4add(c0, c1), f4add(c2, c3)),
                 f4add(f4add(c4, c5), f4add(c6, c7)));
  }
  float4 U0 = f4add(W[0], W[2]);
  float4 U1 = f4add(W[1], W[3]);
  float4 T = f4add(U0, U1);
  float s0 = T.x + T.z, s1 = T.y + T.w;
  return s0 + s1;
}

__global__ __launch_bounds__(256, 2)
void k_t3(const float* __restrict__ cb, float* __restrict__ t3,
          unsigned* __restrict__ t3hl) {
  int k = blockIdx.x * 256 + threadIdx.x;
  float s = np_sumsq_row((const float4*)(cb + (size_t)k * D_));
  t3[k] = s;
  unsigned short h = bf16rne(s);
  unsigned short l = bf16rne(s - bf16tof(h));
  t3hl[k] = (unsigned)h | ((unsigned)l << 16);
}

__global__ __launch_bounds__(256, 2)
void k_t1(const float* __restrict__ x, float* __restrict__ t1) {
  int r = blockIdx.x * 256 + threadIdx.x;
  t1[r] = np_sumsq_row((const float4*)(x + (size_t)r * D_));
}

// codebook -> fragment-linear bf16 hi/lo units.
__global__ __launch_bounds__(256, 2)
void k_prep(const float* __restrict__ cb, const unsigned* __restrict__ t3hl,
            float* __restrict__ outq) {
  int u = blockIdx.x * 256 + threadIdx.x;   // < 73728
  int ch = u / 1152, r = u - ch * 1152;
  int s = r >> 6, p = r & 63;
  int kg = p >> 5, nl = p & 31;
  bf16x8 h = 0, l = 0;
  if (s < 16) {
    int kt = s >> 1, ct = s & 1;
    int code = ch * 64 + ct * 32 + nl;
    const float* src = cb + (size_t)code * D_ + (kt * 2 + kg) * 8;
#pragma unroll
    for (int e = 0; e < 8; ++e) {
      float f = src[e];
      unsigned short hs = bf16rne(f);
      unsigned short ls = bf16rne(f - bf16tof(hs));
      h[e] = (short)hs;
      l[e] = (short)ls;
    }
  } else {
    int ct = s - 16;
    int code = ch * 64 + ct * 32 + nl;
    if (kg == 0) {
      unsigned v = t3hl[code];
      h[0] = (short)(v & 0xFFFFu);
      h[1] = (short)(v >> 16);
    }
  }
  *(bf16x8*)((char*)(outq + OQ_AH) + (size_t)u * 16) = h;
  *(bf16x8*)((char*)(outq + OQ_AL) + (size_t)u * 16) = l;
}

// Approx sweep. 512 thr = 8 waves = 4 row-groups x 2 code-halves.
__global__ __launch_bounds__(512, 2)
void k_big(const float* __restrict__ x, float* __restrict__ outq) {
  extern __shared__ char lds[];
  const int tid = threadIdx.x;
  const int lane = tid & 63;
  const int wid = tid >> 6;
  const int rg = wid >> 1, cs = wid & 1;
  const int kg = lane >> 5, nl = lane & 31;
  const int row0 = blockIdx.x * 256 + rg * 64;

  const char* AhB = (const char*)(outq + OQ_AH);
  const char* AlB = (const char*)(outq + OQ_AL);
  float* cm = outq;   // [64][65536]

  bf16x8 xh[2][8], xl[2][8];
#pragma unroll
  for (int xt = 0; xt < 2; ++xt)
#pragma unroll
    for (int kt = 0; kt < 8; ++kt) {
      const float* src = x + (size_t)(row0 + xt * 32 + nl) * D_ + (kt * 2 + kg) * 8;
      float f[8];
      *(float4*)(f) = *(const float4*)(src);
      *(float4*)(f + 4) = *(const float4*)(src + 4);
      bf16x8 h, l;
#pragma unroll
      for (int e = 0; e < 8; ++e) {
        unsigned short hs = bf16rne(f[e]);
        float hf = bf16tof(hs);
        unsigned short ls = bf16rne(f[e] - hf);
        h[e] = (short)hs;
        l[e] = (short)ls;
      }
      xh[xt][kt] = h;
      xl[xt][kt] = l;
    }

  bf16x8 bneg = 0;
  if (kg == 0) { bneg[0] = (short)0xBF00; bneg[1] = (short)0xBF00; }

  char* half = lds + cs * 73728;

#define STAGE(c, buf)                                                         \
  {                                                                           \
    const char* sAh = AhB + (size_t)(c) * 18432;                              \
    const char* sAl = AlB + (size_t)(c) * 18432;                              \
    _Pragma("unroll")                                                         \
    for (int it9 = 0; it9 < 9; ++it9) {                                       \
      int ub = it9 * 256 + rg * 64;                                           \
      int uu = ub + lane;                                                     \
      if (ub < 1152) gload_lds16(sAh + (size_t)uu * 16, (buf) + ub * 16);     \
      else gload_lds16(sAl + (size_t)(uu - 1152) * 16,                        \
                       (buf) + 18432 + (ub - 1152) * 16);                     \
    }                                                                         \
  }

  STAGE(cs * 32 + 0, half + 0);
  __syncthreads();

  int b = 0;
  for (int it = 0; it < 32; ++it) {
    char* cur = half + b * 36864;
    if (it < 31) STAGE(cs * 32 + it + 1, half + (b ^ 1) * 36864);

    f32x16 a00 = 0, a01 = 0, a10 = 0, a11 = 0;
#pragma unroll
    for (int kt = 0; kt < 8; ++kt) {
      bf16x8 eh0 = *(const bf16x8*)(cur + ((kt * 2 + 0) * 64 + lane) * 16);
      bf16x8 eh1 = *(const bf16x8*)(cur + ((kt * 2 + 1) * 64 + lane) * 16);
      bf16x8 el0 = *(const bf16x8*)(cur + 18432 + ((kt * 2 + 0) * 64 + lane) * 16);
      bf16x8 el1 = *(const bf16x8*)(cur + 18432 + ((kt * 2 + 1) * 64 + lane) * 16);
      a00 = __builtin_amdgcn_mfma_f32_32x32x16_bf16(eh0, xh[0][kt], a00, 0, 0, 0);
      a00 = __builtin_amdgcn_mfma_f32_32x32x16_bf16(el0, xh[0][kt], a00, 0, 0, 0);
      a00 = __builtin_amdgcn_mfma_f32_32x32x16_bf16(eh0, xl[0][kt], a00, 0, 0, 0);
      a01 = __builtin_amdgcn_mfma_f32_32x32x16_bf16(eh0, xh[1][kt], a01, 0, 0, 0);
      a01 = __builtin_amdgcn_mfma_f32_32x32x16_bf16(el0, xh[1][kt], a01, 0, 0, 0);
      a01 = __builtin_amdgcn_mfma_f32_32x32x16_bf16(eh0, xl[1][kt], a01, 0, 0, 0);
      a10 = __builtin_amdgcn_mfma_f32_32x32x16_bf16(eh1, xh[0][kt], a10, 0, 0, 0);
      a10 = __builtin_amdgcn_mfma_f32_32x32x16_bf16(el1, xh[0][kt], a10, 0, 0, 0);
      a10 = __builtin_amdgcn_mfma_f32_32x32x16_bf16(eh1, xl[0][kt], a10, 0, 0, 0);
      a11 = __builtin_amdgcn_mfma_f32_32x32x16_bf16(eh1, xh[1][kt], a11, 0, 0, 0);
      a11 = __builtin_amdgcn_mfma_f32_32x32x16_bf16(el1, xh[1][kt], a11, 0, 0, 0);
      a11 = __builtin_amdgcn_mfma_f32_32x32x16_bf16(eh1, xl[1][kt], a11, 0, 0, 0);
    }
    {
      bf16x8 t30 = *(const bf16x8*)(cur + ((16 + 0) * 64 + lane) * 16);
      bf16x8 t31 = *(const bf16x8*)(cur + ((16 + 1) * 64 + lane) * 16);
      a00 = __builtin_amdgcn_mfma_f32_32x32x16_bf16(t30, bneg, a00, 0, 0, 0);
      a01 = __builtin_amdgcn_mfma_f32_32x32x16_bf16(t30, bneg, a01, 0, 0, 0);
      a10 = __builtin_amdgcn_mfma_f32_32x32x16_bf16(t31, bneg, a10, 0, 0, 0);
      a11 = __builtin_amdgcn_mfma_f32_32x32x16_bf16(t31, bneg, a11, 0, 0, 0);
    }

    float m0 = -3.4e38f, m1v = -3.4e38f;
#pragma unroll
    for (int e = 0; e < 16; ++e) {
      m0 = fmaxf(m0, fmaxf(a00[e], a10[e]));
      m1v = fmaxf(m1v, fmaxf(a01[e], a11[e]));
    }
    m0 = fmaxf(m0, __shfl_xor(m0, 32, 64));
    m1v = fmaxf(m1v, __shfl_xor(m1v, 32, 64));
    if (lane < 32) {
      size_t base = (size_t)(cs * 32 + it) * MROWS + row0;
      cm[base + nl] = m0;
      cm[base + 32 + nl] = m1v;
    }
    __syncthreads();
    b ^= 1;
  }
#undef STAGE
}

// Per row: 64 chunk-maxes into registers (64 independent coalesced loads,
// fully unrolled -> pipelined), then max + threshold pass from registers.
__global__ __launch_bounds__(256, 2)
void k_cand(const float* __restrict__ cm, int* __restrict__ cnt,
            int* __restrict__ pairs, unsigned long long* __restrict__ keys,
            float dlt) {
  int r = blockIdx.x * 256 + threadIdx.x;
  float v[64];
#pragma unroll
  for (int ch = 0; ch < 64; ++ch) v[ch] = cm[(size_t)ch * MROWS + r];
  float A = -3.4e38f;
#pragma unroll
  for (int ch = 0; ch < 64; ++ch) A = fmaxf(A, v[ch]);
  keys[r] = ~0ull;
  float thr = A - dlt;
#pragma unroll
  for (int ch = 0; ch < 64; ++ch) {
    if (v[ch] >= thr) {
      int s = atomicAdd(cnt + ch, 1);
      if (s < ECAP) pairs[ch * ECAP + s] = r;
    }
  }
}

// np-bit-exact rescore of candidate chunks.
__global__ __launch_bounds__(256, 2)
void k_exact(const float* __restrict__ x, const float* __restrict__ cb,
             const int* __restrict__ cnt, const int* __restrict__ pairs,
             const float* __restrict__ t1, const float* __restrict__ t3,
             unsigned long long* __restrict__ keys) {
  __shared__ float elds[32 * 65 * 4];
  __shared__ float xlds[4][D_];
  int ch = blockIdx.x >> 4, sub = blockIdx.x & 15;
  int tid = threadIdx.x, lane = tid & 63, wid = tid >> 6;
#pragma unroll
  for (int it2 = 0; it2 < 8; ++it2) {
    int u = it2 * 256 + tid;        // 0..2047
    int c = u >> 5, d4 = u & 31;
    float4 v = *(const float4*)(cb + ((size_t)ch * 64 + c) * D_ + d4 * 4);
    *(float4*)(elds + (d4 * 65 + c) * 4) = v;
  }
  float t3v = t3[ch * 64 + lane];
  __syncthreads();
  int n = cnt[ch]; if (n > ECAP) n = ECAP;
  int start = (sub * n) >> 4, end = ((sub + 1) * n) >> 4;
  for (int idx = start + wid; idx < end; idx += 4) {
    int row = pairs[ch * ECAP + idx];
    *(float2*)(&xlds[wid][lane * 2]) = *(const float2*)(x + (size_t)row * D_ + lane * 2);
    asm volatile("s_waitcnt lgkmcnt(0)" ::: "memory");
    float acc = 0.f;
    float t1r = t1[row];
#pragma unroll 8
    for (int d4 = 0; d4 < 32; ++d4) {
      float4 xv = *(const float4*)(&xlds[wid][d4 * 4]);
      float4 ev = *(const float4*)(elds + (d4 * 65 + lane) * 4);
      acc = __builtin_fmaf(xv.x, ev.x, acc);
      acc = __builtin_fmaf(xv.y, ev.y, acc);
      acc = __builtin_fmaf(xv.z, ev.z, acc);
      acc = __builtin_fmaf(xv.w, ev.w, acc);
    }
    float s = __builtin_fmaf(-2.f, acc, t1r) + t3v;
    unsigned u32 = __float_as_uint(s);
    u32 = u32 ^ (unsigned)(((int)u32 >> 31) | 0x80000000);
    unsigned long long key =
        ((unsigned long long)u32 << 12) | (unsigned)(ch * 64 + lane);
#pragma unroll
    for (int off = 1; off < 64; off <<= 1) {
      unsigned long long o = __shfl_xor(key, off, 64);
      key = o < key ? o : key;
    }
    if (lane == 0) atomicMin(keys + row, key);
  }
}

__global__ __launch_bounds__(256, 2)
void k_final(const unsigned long long* __restrict__ keys,
             float* __restrict__ tok_f, int* __restrict__ tok_i) {
  int r = blockIdx.x * 256 + threadIdx.x;
  int code = (int)(keys[r] & 0xFFFull);
  tok_f[r] = (float)code;
  tok_i[r] = code;
}

__global__ __launch_bounds__(256, 2)
void k_gather(const float* __restrict__ x, const float* __restrict__ cb,
              const int* __restrict__ tok_i, float* __restrict__ outq,
              float* __restrict__ partial) {
  int idx = blockIdx.x * 256 + threadIdx.x;
  int row = idx >> 5;
  int d4 = idx & 31;
  int t = tok_i[row];
  float4 q = ((const float4*)(cb + (size_t)t * D_))[d4];
  float4 xv = ((const float4*)x)[idx];
  ((float4*)outq)[idx] = q;
  float dx = q.x - xv.x, dy = q.y - xv.y, dz = q.z - xv.z, dw = q.w - xv.w;
  float s = dx * dx + dy * dy + dz * dz + dw * dw;
#pragma unroll
  for (int off = 1; off < 64; off <<= 1) s += __shfl_xor(s, off, 64);
  __shared__ float red[4];
  int lane = threadIdx.x & 63, w = threadIdx.x >> 6;
  if (lane == 0) red[w] = s;
  __syncthreads();
  if (threadIdx.x == 0)
    partial[blockIdx.x] = red[0] + red[1] + red[2] + red[3];
}

__global__ __launch_bounds__(256, 1)
void k_loss(const float* __restrict__ partial, int n, float* __restrict__ out_loss,
            float scale) {
  float s = 0.f;
  for (int i = threadIdx.x; i < n; i += 256) s += partial[i];
#pragma unroll
  for (int off = 1; off < 64; off <<= 1) s += __shfl_xor(s, off, 64);
  __shared__ float red[4];
  int lane = threadIdx.x & 63, w = threadIdx.x >> 6;
  if (lane == 0) red[w] = s;
  __syncthreads();
  if (threadIdx.x == 0)
    out_loss[0] = (red[0] + red[1] + red[2] + red[3]) * scale;
}

extern "C" void kernel_launch(void* const* d_in, const int* in_sizes, int n_in,
                              void* d_out, int out_size, void* d_ws, size_t ws_size,
                              hipStream_t stream) {
  const float* x = (const float*)d_in[0];
  const float* cb = (const float*)d_in[1];

  float* out_tok = (float*)d_out;
  float* outq = (float*)d_out + MROWS;
  float* out_loss = (float*)d_out + MROWS + (size_t)MROWS * D_;

  int* tok_i = (int*)d_ws;                          // 256 KB
  float* part = (float*)((char*)d_ws + 262144);     // 32 KB

  float* t3 = outq + OQ_T3;
  float* t1 = outq + OQ_T1;
  unsigned* t3hl = (unsigned*)(outq + OQ_T3HL);
  int* cnt = (int*)(outq + OQ_CNT);
  int* pairs = (int*)(outq + OQ_PAIRS);
  unsigned long long* keys = (unsigned long long*)(outq + OQ_KEYS);

  k_t3<<<KCODES / 256, 256, 0, stream>>>(cb, t3, t3hl);
  k_t1<<<MROWS / 256, 256, 0, stream>>>(x, t1);
  k_prep<<<(64 * 1152) / 256, 256, 0, stream>>>(cb, t3hl, outq);
  k_big<<<MROWS / 256, 512, 147456, stream>>>(x, outq);
  hipMemsetAsync(cnt, 0, 64 * sizeof(int), stream);
  k_cand<<<MROWS / 256, 256, 0, stream>>>(outq, cnt, pairs, keys, 2e-3f);
  k_exact<<<64 * 16, 256, 0, stream>>>(x, cb, cnt, pairs, t1, t3, keys);
  k_final<<<MROWS / 256, 256, 0, stream>>>(keys, out_tok, tok_i);
  const int gB = (MROWS * (D_ / 4)) / 256;
  k_gather<<<gB, 256, 0, stream>>>(x, cb, tok_i, outq, part);
  k_loss<<<1, 256, 0, stream>>>(part, gB, out_loss,
                                1.5f / (float)((size_t)MROWS * D_));
}

// Round 6
// 599.008 us; speedup vs baseline: 2.0145x; 1.1400x over previous
//
#include <hip/hip_runtime.h>

// SharedVectorQuantizer forward, MI355X. x:[65536,128]f32 cb:[4096,128]f32
// out: tokens[M] (float) | quantized[M*128] | vq_loss[1]
//
// Pipeline: k_t3 (np ||e||^2 + bf16 split), k_t1 (np ||x||^2), k_prep
// (codebook -> bf16 hi/lo, fragment-linear chunk layout + t3 MFMA slab),
// k_big (bf16-split MFMA approx: per (row, 64-code chunk) max of acc;
// score = -2*acc), k_cand (per row: chunks within delta of best -> pairs),
// k_exact (np-bit-exact fp32 chain rescore of candidate chunks, u64
// atomicMin of (score_bits<<12)|code), k_final, k_gather, k_loss.
//
// Big scratch lives in the quantized-output region (dead before k_gather).

#define D_ 128
#define MROWS 65536
#define KCODES 4096
#define ECAP 2048

// float offsets within out_q scratch region (8388608 floats)
#define OQ_AH    4194304   // 64 chunks * 1152 units * 16B (bf16 hi, +t3 slabs)
#define OQ_AL    4489216   // bf16 lo (padded to 1152 units/chunk)
#define OQ_KEYS  4784128   // u64[65536]
#define OQ_PAIRS 4915200   // int[64*ECAP]
#define OQ_T1    5046272   // f32[65536]
#define OQ_T3    5111808   // f32[4096]
#define OQ_T3HL  5115904   // u32[4096] packed t3h | t3l<<16
#define OQ_CNT   5120000   // int[64]

typedef __attribute__((ext_vector_type(8))) short bf16x8;
typedef __attribute__((ext_vector_type(16))) float f32x16;

__device__ __forceinline__ unsigned short bf16rne(float f) {
  unsigned u = __float_as_uint(f);
  unsigned r = (u + 0x7FFFu + ((u >> 16) & 1u)) >> 16;
  return (unsigned short)r;
}
__device__ __forceinline__ float bf16tof(unsigned short h) {
  return __uint_as_float(((unsigned)h) << 16);
}

__device__ __forceinline__ void gload_lds16(const void* g, void* l) {
  __builtin_amdgcn_global_load_lds(
      (const __attribute__((address_space(1))) unsigned int*)g,
      (__attribute__((address_space(3))) unsigned int*)l, 16, 0, 0);
}

__device__ __forceinline__ float4 f4add(float4 a, float4 b) {
  return make_float4(a.x + b.x, a.y + b.y, a.z + b.z, a.w + b.w);
}
__device__ __forceinline__ float4 f4sq(float4 v) {
  return make_float4(v.x * v.x, v.y * v.y, v.z * v.z, v.w * v.w);
}

// numpy fp32 pairwise sum of squares, AVX-512 npyv path (verified round 3)
__device__ __forceinline__ float np_sumsq_row(const float4* __restrict__ r) {
  float4 W[4];
#pragma unroll
  for (int a = 0; a < 4; ++a) {
    float4 c0 = f4sq(r[0 * 4 + a]), c1 = f4sq(r[1 * 4 + a]);
    float4 c2 = f4sq(r[2 * 4 + a]), c3 = f4sq(r[3 * 4 + a]);
    float4 c4 = f4sq(r[4 * 4 + a]), c5 = f4sq(r[5 * 4 + a]);
    float4 c6 = f4sq(r[6 * 4 + a]), c7 = f4sq(r[7 * 4 + a]);
    W[a] = f4add(f4add(f4add(c0, c1), f4add(c2, c3)),
                 f4add(f4add(c4, c5), f4add(c6, c7)));
  }
  float4 U0 = f4add(W[0], W[2]);
  float4 U1 = f4add(W[1], W[3]);
  float4 T = f4add(U0, U1);
  float s0 = T.x + T.z, s1 = T.y + T.w;
  return s0 + s1;
}

__global__ __launch_bounds__(256, 2)
void k_t3(const float* __restrict__ cb, float* __restrict__ t3,
          unsigned* __restrict__ t3hl) {
  int k = blockIdx.x * 256 + threadIdx.x;
  float s = np_sumsq_row((const float4*)(cb + (size_t)k * D_));
  t3[k] = s;
  unsigned short h = bf16rne(s);
  unsigned short l = bf16rne(s - bf16tof(h));
  t3hl[k] = (unsigned)h | ((unsigned)l << 16);
}

__global__ __launch_bounds__(256, 2)
void k_t1(const float* __restrict__ x, float* __restrict__ t1) {
  int r = blockIdx.x * 256 + threadIdx.x;
  t1[r] = np_sumsq_row((const float4*)(x + (size_t)r * D_));
}

// codebook -> fragment-linear bf16 hi/lo units.
__global__ __launch_bounds__(256, 2)
void k_prep(const float* __restrict__ cb, const unsigned* __restrict__ t3hl,
            float* __restrict__ outq) {
  int u = blockIdx.x * 256 + threadIdx.x;   // < 73728
  int ch = u / 1152, r = u - ch * 1152;
  int s = r >> 6, p = r & 63;
  int kg = p >> 5, nl = p & 31;
  bf16x8 h = 0, l = 0;
  if (s < 16) {
    int kt = s >> 1, ct = s & 1;
    int code = ch * 64 + ct * 32 + nl;
    const float* src = cb + (size_t)code * D_ + (kt * 2 + kg) * 8;
#pragma unroll
    for (int e = 0; e < 8; ++e) {
      float f = src[e];
      unsigned short hs = bf16rne(f);
      unsigned short ls = bf16rne(f - bf16tof(hs));
      h[e] = (short)hs;
      l[e] = (short)ls;
    }
  } else {
    int ct = s - 16;
    int code = ch * 64 + ct * 32 + nl;
    if (kg == 0) {
      unsigned v = t3hl[code];
      h[0] = (short)(v & 0xFFFFu);
      h[1] = (short)(v >> 16);
    }
  }
  *(bf16x8*)((char*)(outq + OQ_AH) + (size_t)u * 16) = h;
  *(bf16x8*)((char*)(outq + OQ_AL) + (size_t)u * 16) = l;
}

// Approx sweep. 512 thr = 8 waves = 4 row-groups x 2 code-halves.
__global__ __launch_bounds__(512, 2)
void k_big(const float* __restrict__ x, float* __restrict__ outq) {
  extern __shared__ char lds[];
  const int tid = threadIdx.x;
  const int lane = tid & 63;
  const int wid = tid >> 6;
  const int rg = wid >> 1, cs = wid & 1;
  const int kg = lane >> 5, nl = lane & 31;
  const int row0 = blockIdx.x * 256 + rg * 64;

  const char* AhB = (const char*)(outq + OQ_AH);
  const char* AlB = (const char*)(outq + OQ_AL);
  float* cm = outq;   // [64][65536]

  bf16x8 xh[2][8], xl[2][8];
#pragma unroll
  for (int xt = 0; xt < 2; ++xt)
#pragma unroll
    for (int kt = 0; kt < 8; ++kt) {
      const float* src = x + (size_t)(row0 + xt * 32 + nl) * D_ + (kt * 2 + kg) * 8;
      float f[8];
      *(float4*)(f) = *(const float4*)(src);
      *(float4*)(f + 4) = *(const float4*)(src + 4);
      bf16x8 h, l;
#pragma unroll
      for (int e = 0; e < 8; ++e) {
        unsigned short hs = bf16rne(f[e]);
        float hf = bf16tof(hs);
        unsigned short ls = bf16rne(f[e] - hf);
        h[e] = (short)hs;
        l[e] = (short)ls;
      }
      xh[xt][kt] = h;
      xl[xt][kt] = l;
    }

  bf16x8 bneg = 0;
  if (kg == 0) { bneg[0] = (short)0xBF00; bneg[1] = (short)0xBF00; }

  char* half = lds + cs * 73728;

#define STAGE(c, buf)                                                         \
  {                                                                           \
    const char* sAh = AhB + (size_t)(c) * 18432;                              \
    const char* sAl = AlB + (size_t)(c) * 18432;                              \
    _Pragma("unroll")                                                         \
    for (int it9 = 0; it9 < 9; ++it9) {                                       \
      int ub = it9 * 256 + rg * 64;                                           \
      int uu = ub + lane;                                                     \
      if (ub < 1152) gload_lds16(sAh + (size_t)uu * 16, (buf) + ub * 16);     \
      else gload_lds16(sAl + (size_t)(uu - 1152) * 16,                        \
                       (buf) + 18432 + (ub - 1152) * 16);                     \
    }                                                                         \
  }

  STAGE(cs * 32 + 0, half + 0);
  __syncthreads();

  int b = 0;
  for (int it = 0; it < 32; ++it) {
    char* cur = half + b * 36864;
    if (it < 31) STAGE(cs * 32 + it + 1, half + (b ^ 1) * 36864);

    f32x16 a00 = 0, a01 = 0, a10 = 0, a11 = 0;
#pragma unroll
    for (int kt = 0; kt < 8; ++kt) {
      bf16x8 eh0 = *(const bf16x8*)(cur + ((kt * 2 + 0) * 64 + lane) * 16);
      bf16x8 eh1 = *(const bf16x8*)(cur + ((kt * 2 + 1) * 64 + lane) * 16);
      bf16x8 el0 = *(const bf16x8*)(cur + 18432 + ((kt * 2 + 0) * 64 + lane) * 16);
      bf16x8 el1 = *(const bf16x8*)(cur + 18432 + ((kt * 2 + 1) * 64 + lane) * 16);
      a00 = __builtin_amdgcn_mfma_f32_32x32x16_bf16(eh0, xh[0][kt], a00, 0, 0, 0);
      a00 = __builtin_amdgcn_mfma_f32_32x32x16_bf16(el0, xh[0][kt], a00, 0, 0, 0);
      a00 = __builtin_amdgcn_mfma_f32_32x32x16_bf16(eh0, xl[0][kt], a00, 0, 0, 0);
      a01 = __builtin_amdgcn_mfma_f32_32x32x16_bf16(eh0, xh[1][kt], a01, 0, 0, 0);
      a01 = __builtin_amdgcn_mfma_f32_32x32x16_bf16(el0, xh[1][kt], a01, 0, 0, 0);
      a01 = __builtin_amdgcn_mfma_f32_32x32x16_bf16(eh0, xl[1][kt], a01, 0, 0, 0);
      a10 = __builtin_amdgcn_mfma_f32_32x32x16_bf16(eh1, xh[0][kt], a10, 0, 0, 0);
      a10 = __builtin_amdgcn_mfma_f32_32x32x16_bf16(el1, xh[0][kt], a10, 0, 0, 0);
      a10 = __builtin_amdgcn_mfma_f32_32x32x16_bf16(eh1, xl[0][kt], a10, 0, 0, 0);
      a11 = __builtin_amdgcn_mfma_f32_32x32x16_bf16(eh1, xh[1][kt], a11, 0, 0, 0);
      a11 = __builtin_amdgcn_mfma_f32_32x32x16_bf16(el1, xh[1][kt], a11, 0, 0, 0);
      a11 = __builtin_amdgcn_mfma_f32_32x32x16_bf16(eh1, xl[1][kt], a11, 0, 0, 0);
    }
    {
      bf16x8 t30 = *(const bf16x8*)(cur + ((16 + 0) * 64 + lane) * 16);
      bf16x8 t31 = *(const bf16x8*)(cur + ((16 + 1) * 64 + lane) * 16);
      a00 = __builtin_amdgcn_mfma_f32_32x32x16_bf16(t30, bneg, a00, 0, 0, 0);
      a01 = __builtin_amdgcn_mfma_f32_32x32x16_bf16(t30, bneg, a01, 0, 0, 0);
      a10 = __builtin_amdgcn_mfma_f32_32x32x16_bf16(t31, bneg, a10, 0, 0, 0);
      a11 = __builtin_amdgcn_mfma_f32_32x32x16_bf16(t31, bneg, a11, 0, 0, 0);
    }

    float m0 = -3.4e38f, m1v = -3.4e38f;
#pragma unroll
    for (int e = 0; e < 16; ++e) {
      m0 = fmaxf(m0, fmaxf(a00[e], a10[e]));
      m1v = fmaxf(m1v, fmaxf(a01[e], a11[e]));
    }
    m0 = fmaxf(m0, __shfl_xor(m0, 32, 64));
    m1v = fmaxf(m1v, __shfl_xor(m1v, 32, 64));
    if (lane < 32) {
      size_t base = (size_t)(cs * 32 + it) * MROWS + row0;
      cm[base + nl] = m0;
      cm[base + 32 + nl] = m1v;
    }
    __syncthreads();
    b ^= 1;
  }
#undef STAGE
}

// Candidate select, tile form: block = 256 thr = 4 waves covers 64 rows.
// Wave w loads chunks w*16..w*16+15 for rows r0..r0+63 -- every load is a
// contiguous 64-lane coalesced 4B access; 16 independent loads per thread.
// Grid 1024 blocks -> 4 blocks/CU (vs 1 before): latency actually hidden.
__global__ __launch_bounds__(256, 4)
void k_cand(const float* __restrict__ cm, int* __restrict__ cnt,
            int* __restrict__ pairs, unsigned long long* __restrict__ keys,
            float dlt) {
  __shared__ float wmax[4][64];
  __shared__ float thrs[64];
  const int tid = threadIdx.x, lane = tid & 63, w = tid >> 6;
  const int r = blockIdx.x * 64 + lane;
  float v[16];
#pragma unroll
  for (int i = 0; i < 16; ++i) v[i] = cm[(size_t)(w * 16 + i) * MROWS + r];
  float m = v[0];
#pragma unroll
  for (int i = 1; i < 16; ++i) m = fmaxf(m, v[i]);
  wmax[w][lane] = m;
  __syncthreads();
  if (w == 0) {
    float A = fmaxf(fmaxf(wmax[0][lane], wmax[1][lane]),
                    fmaxf(wmax[2][lane], wmax[3][lane]));
    thrs[lane] = A - dlt;
    keys[r] = ~0ull;
  }
  __syncthreads();
  float thr = thrs[lane];
#pragma unroll
  for (int i = 0; i < 16; ++i) {
    if (v[i] >= thr) {
      int ch = w * 16 + i;
      int s = atomicAdd(cnt + ch, 1);
      if (s < ECAP) pairs[ch * ECAP + s] = r;
    }
  }
}

// np-bit-exact rescore of candidate chunks.
__global__ __launch_bounds__(256, 2)
void k_exact(const float* __restrict__ x, const float* __restrict__ cb,
             const int* __restrict__ cnt, const int* __restrict__ pairs,
             const float* __restrict__ t1, const float* __restrict__ t3,
             unsigned long long* __restrict__ keys) {
  __shared__ float elds[32 * 65 * 4];
  __shared__ float xlds[4][D_];
  int ch = blockIdx.x >> 4, sub = blockIdx.x & 15;
  int tid = threadIdx.x, lane = tid & 63, wid = tid >> 6;
#pragma unroll
  for (int it2 = 0; it2 < 8; ++it2) {
    int u = it2 * 256 + tid;        // 0..2047
    int c = u >> 5, d4 = u & 31;
    float4 v = *(const float4*)(cb + ((size_t)ch * 64 + c) * D_ + d4 * 4);
    *(float4*)(elds + (d4 * 65 + c) * 4) = v;
  }
  float t3v = t3[ch * 64 + lane];
  __syncthreads();
  int n = cnt[ch]; if (n > ECAP) n = ECAP;
  int start = (sub * n) >> 4, end = ((sub + 1) * n) >> 4;
  for (int idx = start + wid; idx < end; idx += 4) {
    int row = pairs[ch * ECAP + idx];
    *(float2*)(&xlds[wid][lane * 2]) = *(const float2*)(x + (size_t)row * D_ + lane * 2);
    asm volatile("s_waitcnt lgkmcnt(0)" ::: "memory");
    float acc = 0.f;
    float t1r = t1[row];
#pragma unroll 8
    for (int d4 = 0; d4 < 32; ++d4) {
      float4 xv = *(const float4*)(&xlds[wid][d4 * 4]);
      float4 ev = *(const float4*)(elds + (d4 * 65 + lane) * 4);
      acc = __builtin_fmaf(xv.x, ev.x, acc);
      acc = __builtin_fmaf(xv.y, ev.y, acc);
      acc = __builtin_fmaf(xv.z, ev.z, acc);
      acc = __builtin_fmaf(xv.w, ev.w, acc);
    }
    float s = __builtin_fmaf(-2.f, acc, t1r) + t3v;
    unsigned u32 = __float_as_uint(s);
    u32 = u32 ^ (unsigned)(((int)u32 >> 31) | 0x80000000);
    unsigned long long key =
        ((unsigned long long)u32 << 12) | (unsigned)(ch * 64 + lane);
#pragma unroll
    for (int off = 1; off < 64; off <<= 1) {
      unsigned long long o = __shfl_xor(key, off, 64);
      key = o < key ? o : key;
    }
    if (lane == 0) atomicMin(keys + row, key);
  }
}

__global__ __launch_bounds__(256, 2)
void k_final(const unsigned long long* __restrict__ keys,
             float* __restrict__ tok_f, int* __restrict__ tok_i) {
  int r = blockIdx.x * 256 + threadIdx.x;
  int code = (int)(keys[r] & 0xFFFull);
  tok_f[r] = (float)code;
  tok_i[r] = code;
}

__global__ __launch_bounds__(256, 2)
void k_gather(const float* __restrict__ x, const float* __restrict__ cb,
              const int* __restrict__ tok_i, float* __restrict__ outq,
              float* __restrict__ partial) {
  int idx = blockIdx.x * 256 + threadIdx.x;
  int row = idx >> 5;
  int d4 = idx & 31;
  int t = tok_i[row];
  float4 q = ((const float4*)(cb + (size_t)t * D_))[d4];
  float4 xv = ((const float4*)x)[idx];
  ((float4*)outq)[idx] = q;
  float dx = q.x - xv.x, dy = q.y - xv.y, dz = q.z - xv.z, dw = q.w - xv.w;
  float s = dx * dx + dy * dy + dz * dz + dw * dw;
#pragma unroll
  for (int off = 1; off < 64; off <<= 1) s += __shfl_xor(s, off, 64);
  __shared__ float red[4];
  int lane = threadIdx.x & 63, w = threadIdx.x >> 6;
  if (lane == 0) red[w] = s;
  __syncthreads();
  if (threadIdx.x == 0)
    partial[blockIdx.x] = red[0] + red[1] + red[2] + red[3];
}

__global__ __launch_bounds__(256, 1)
void k_loss(const float* __restrict__ partial, int n, float* __restrict__ out_loss,
            float scale) {
  float s = 0.f;
  for (int i = threadIdx.x; i < n; i += 256) s += partial[i];
#pragma unroll
  for (int off = 1; off < 64; off <<= 1) s += __shfl_xor(s, off, 64);
  __shared__ float red[4];
  int lane = threadIdx.x & 63, w = threadIdx.x >> 6;
  if (lane == 0) red[w] = s;
  __syncthreads();
  if (threadIdx.x == 0)
    out_loss[0] = (red[0] + red[1] + red[2] + red[3]) * scale;
}

extern "C" void kernel_launch(void* const* d_in, const int* in_sizes, int n_in,
                              void* d_out, int out_size, void* d_ws, size_t ws_size,
                              hipStream_t stream) {
  const float* x = (const float*)d_in[0];
  const float* cb = (const float*)d_in[1];

  float* out_tok = (float*)d_out;
  float* outq = (float*)d_out + MROWS;
  float* out_loss = (float*)d_out + MROWS + (size_t)MROWS * D_;

  int* tok_i = (int*)d_ws;                          // 256 KB
  float* part = (float*)((char*)d_ws + 262144);     // 32 KB

  float* t3 = outq + OQ_T3;
  float* t1 = outq + OQ_T1;
  unsigned* t3hl = (unsigned*)(outq + OQ_T3HL);
  int* cnt = (int*)(outq + OQ_CNT);
  int* pairs = (int*)(outq + OQ_PAIRS);
  unsigned long long* keys = (unsigned long long*)(outq + OQ_KEYS);

  k_t3<<<KCODES / 256, 256, 0, stream>>>(cb, t3, t3hl);
  k_t1<<<MROWS / 256, 256, 0, stream>>>(x, t1);
  k_prep<<<(64 * 1152) / 256, 256, 0, stream>>>(cb, t3hl, outq);
  k_big<<<MROWS / 256, 512, 147456, stream>>>(x, outq);
  hipMemsetAsync(cnt, 0, 64 * sizeof(int), stream);
  k_cand<<<MROWS / 64, 256, 0, stream>>>(outq, cnt, pairs, keys, 2e-3f);
  k_exact<<<64 * 16, 256, 0, stream>>>(x, cb, cnt, pairs, t1, t3, keys);
  k_final<<<MROWS / 256, 256, 0, stream>>>(keys, out_tok, tok_i);
  const int gB = (MROWS * (D_ / 4)) / 256;
  k_gather<<<gB, 256, 0, stream>>>(x, cb, tok_i, outq, part);
  k_loss<<<1, 256, 0, stream>>>(part, gB, out_loss,
                                1.5f / (float)((size_t)MROWS * D_));
}

// Round 7
// 297.206 us; speedup vs baseline: 4.0602x; 2.0155x over previous
//
#include <hip/hip_runtime.h>

// SharedVectorQuantizer forward, MI355X. x:[65536,128]f32 cb:[4096,128]f32
// out: tokens[M] (float) | quantized[M*128] | vq_loss[1]
//
// Pipeline: k_t3 (np ||e||^2 + bf16 split), k_t1 (np ||x||^2), k_prep
// (codebook -> bf16 hi/lo, fragment-linear chunk layout + t3 MFMA slab),
// k_big (bf16-split MFMA approx: per (row, 64-code chunk) max of acc;
// score = -2*acc), k_cand (per row: chunks within delta of best -> pairs,
// sub-bucketed counters: one cacheline each, no atomic contention),
// k_exact (np-bit-exact fp32 chain rescore, u64 atomicMin), k_final,
// k_gather, k_loss.
//
// Big scratch lives in the quantized-output region (dead before k_gather).

#define D_ 128
#define MROWS 65536
#define KCODES 4096
#define NSUB 16
#define SUBCAP 512

// float offsets within out_q scratch region (8388608 floats)
#define OQ_AH    4194304   // 64 chunks * 1152 units * 16B (bf16 hi, +t3 slabs)
#define OQ_AL    4489216   // bf16 lo
#define OQ_KEYS  4784128   // u64[65536]
#define OQ_PAIRS 4915200   // int[64*NSUB*SUBCAP] = 524288
#define OQ_T1    5439488   // f32[65536]
#define OQ_T3    5505024   // f32[4096]
#define OQ_T3HL  5509120   // u32[4096] packed t3h | t3l<<16
#define OQ_CNT   5513216   // int[64*NSUB*16]  (each counter on its own 64B line)

typedef __attribute__((ext_vector_type(8))) short bf16x8;
typedef __attribute__((ext_vector_type(16))) float f32x16;

__device__ __forceinline__ unsigned short bf16rne(float f) {
  unsigned u = __float_as_uint(f);
  unsigned r = (u + 0x7FFFu + ((u >> 16) & 1u)) >> 16;
  return (unsigned short)r;
}
__device__ __forceinline__ float bf16tof(unsigned short h) {
  return __uint_as_float(((unsigned)h) << 16);
}

__device__ __forceinline__ void gload_lds16(const void* g, void* l) {
  __builtin_amdgcn_global_load_lds(
      (const __attribute__((address_space(1))) unsigned int*)g,
      (__attribute__((address_space(3))) unsigned int*)l, 16, 0, 0);
}

__device__ __forceinline__ float4 f4add(float4 a, float4 b) {
  return make_float4(a.x + b.x, a.y + b.y, a.z + b.z, a.w + b.w);
}
__device__ __forceinline__ float4 f4sq(float4 v) {
  return make_float4(v.x * v.x, v.y * v.y, v.z * v.z, v.w * v.w);
}

// numpy fp32 pairwise sum of squares, AVX-512 npyv path (verified round 3)
__device__ __forceinline__ float np_sumsq_row(const float4* __restrict__ r) {
  float4 W[4];
#pragma unroll
  for (int a = 0; a < 4; ++a) {
    float4 c0 = f4sq(r[0 * 4 + a]), c1 = f4sq(r[1 * 4 + a]);
    float4 c2 = f4sq(r[2 * 4 + a]), c3 = f4sq(r[3 * 4 + a]);
    float4 c4 = f4sq(r[4 * 4 + a]), c5 = f4sq(r[5 * 4 + a]);
    float4 c6 = f4sq(r[6 * 4 + a]), c7 = f4sq(r[7 * 4 + a]);
    W[a] = f4add(f4add(f4add(c0, c1), f4add(c2, c3)),
                 f4add(f4add(c4, c5), f4add(c6, c7)));
  }
  float4 U0 = f4add(W[0], W[2]);
  float4 U1 = f4add(W[1], W[3]);
  float4 T = f4add(U0, U1);
  float s0 = T.x + T.z, s1 = T.y + T.w;
  return s0 + s1;
}

__global__ __launch_bounds__(256, 2)
void k_t3(const float* __restrict__ cb, float* __restrict__ t3,
          unsigned* __restrict__ t3hl) {
  int k = blockIdx.x * 256 + threadIdx.x;
  float s = np_sumsq_row((const float4*)(cb + (size_t)k * D_));
  t3[k] = s;
  unsigned short h = bf16rne(s);
  unsigned short l = bf16rne(s - bf16tof(h));
  t3hl[k] = (unsigned)h | ((unsigned)l << 16);
}

__global__ __launch_bounds__(256, 2)
void k_t1(const float* __restrict__ x, float* __restrict__ t1) {
  int r = blockIdx.x * 256 + threadIdx.x;
  t1[r] = np_sumsq_row((const float4*)(x + (size_t)r * D_));
}

// codebook -> fragment-linear bf16 hi/lo units.
__global__ __launch_bounds__(256, 2)
void k_prep(const float* __restrict__ cb, const unsigned* __restrict__ t3hl,
            float* __restrict__ outq) {
  int u = blockIdx.x * 256 + threadIdx.x;   // < 73728
  int ch = u / 1152, r = u - ch * 1152;
  int s = r >> 6, p = r & 63;
  int kg = p >> 5, nl = p & 31;
  bf16x8 h = 0, l = 0;
  if (s < 16) {
    int kt = s >> 1, ct = s & 1;
    int code = ch * 64 + ct * 32 + nl;
    const float* src = cb + (size_t)code * D_ + (kt * 2 + kg) * 8;
#pragma unroll
    for (int e = 0; e < 8; ++e) {
      float f = src[e];
      unsigned short hs = bf16rne(f);
      unsigned short ls = bf16rne(f - bf16tof(hs));
      h[e] = (short)hs;
      l[e] = (short)ls;
    }
  } else {
    int ct = s - 16;
    int code = ch * 64 + ct * 32 + nl;
    if (kg == 0) {
      unsigned v = t3hl[code];
      h[0] = (short)(v & 0xFFFFu);
      h[1] = (short)(v >> 16);
    }
  }
  *(bf16x8*)((char*)(outq + OQ_AH) + (size_t)u * 16) = h;
  *(bf16x8*)((char*)(outq + OQ_AL) + (size_t)u * 16) = l;
}

// Approx sweep. 512 thr = 8 waves = 4 row-groups x 2 code-halves.
__global__ __launch_bounds__(512, 2)
void k_big(const float* __restrict__ x, float* __restrict__ outq) {
  extern __shared__ char lds[];
  const int tid = threadIdx.x;
  const int lane = tid & 63;
  const int wid = tid >> 6;
  const int rg = wid >> 1, cs = wid & 1;
  const int kg = lane >> 5, nl = lane & 31;
  const int row0 = blockIdx.x * 256 + rg * 64;

  const char* AhB = (const char*)(outq + OQ_AH);
  const char* AlB = (const char*)(outq + OQ_AL);
  float* cm = outq;   // [64][65536]

  bf16x8 xh[2][8], xl[2][8];
#pragma unroll
  for (int xt = 0; xt < 2; ++xt)
#pragma unroll
    for (int kt = 0; kt < 8; ++kt) {
      const float* src = x + (size_t)(row0 + xt * 32 + nl) * D_ + (kt * 2 + kg) * 8;
      float f[8];
      *(float4*)(f) = *(const float4*)(src);
      *(float4*)(f + 4) = *(const float4*)(src + 4);
      bf16x8 h, l;
#pragma unroll
      for (int e = 0; e < 8; ++e) {
        unsigned short hs = bf16rne(f[e]);
        float hf = bf16tof(hs);
        unsigned short ls = bf16rne(f[e] - hf);
        h[e] = (short)hs;
        l[e] = (short)ls;
      }
      xh[xt][kt] = h;
      xl[xt][kt] = l;
    }

  bf16x8 bneg = 0;
  if (kg == 0) { bneg[0] = (short)0xBF00; bneg[1] = (short)0xBF00; }

  char* half = lds + cs * 73728;

#define STAGE(c, buf)                                                         \
  {                                                                           \
    const char* sAh = AhB + (size_t)(c) * 18432;                              \
    const char* sAl = AlB + (size_t)(c) * 18432;                              \
    _Pragma("unroll")                                                         \
    for (int it9 = 0; it9 < 9; ++it9) {                                       \
      int ub = it9 * 256 + rg * 64;                                           \
      int uu = ub + lane;                                                     \
      if (ub < 1152) gload_lds16(sAh + (size_t)uu * 16, (buf) + ub * 16);     \
      else gload_lds16(sAl + (size_t)(uu - 1152) * 16,                        \
                       (buf) + 18432 + (ub - 1152) * 16);                     \
    }                                                                         \
  }

  STAGE(cs * 32 + 0, half + 0);
  __syncthreads();

  int b = 0;
  for (int it = 0; it < 32; ++it) {
    char* cur = half + b * 36864;
    if (it < 31) STAGE(cs * 32 + it + 1, half + (b ^ 1) * 36864);

    f32x16 a00 = 0, a01 = 0, a10 = 0, a11 = 0;
#pragma unroll
    for (int kt = 0; kt < 8; ++kt) {
      bf16x8 eh0 = *(const bf16x8*)(cur + ((kt * 2 + 0) * 64 + lane) * 16);
      bf16x8 eh1 = *(const bf16x8*)(cur + ((kt * 2 + 1) * 64 + lane) * 16);
      bf16x8 el0 = *(const bf16x8*)(cur + 18432 + ((kt * 2 + 0) * 64 + lane) * 16);
      bf16x8 el1 = *(const bf16x8*)(cur + 18432 + ((kt * 2 + 1) * 64 + lane) * 16);
      a00 = __builtin_amdgcn_mfma_f32_32x32x16_bf16(eh0, xh[0][kt], a00, 0, 0, 0);
      a00 = __builtin_amdgcn_mfma_f32_32x32x16_bf16(el0, xh[0][kt], a00, 0, 0, 0);
      a00 = __builtin_amdgcn_mfma_f32_32x32x16_bf16(eh0, xl[0][kt], a00, 0, 0, 0);
      a01 = __builtin_amdgcn_mfma_f32_32x32x16_bf16(eh0, xh[1][kt], a01, 0, 0, 0);
      a01 = __builtin_amdgcn_mfma_f32_32x32x16_bf16(el0, xh[1][kt], a01, 0, 0, 0);
      a01 = __builtin_amdgcn_mfma_f32_32x32x16_bf16(eh0, xl[1][kt], a01, 0, 0, 0);
      a10 = __builtin_amdgcn_mfma_f32_32x32x16_bf16(eh1, xh[0][kt], a10, 0, 0, 0);
      a10 = __builtin_amdgcn_mfma_f32_32x32x16_bf16(el1, xh[0][kt], a10, 0, 0, 0);
      a10 = __builtin_amdgcn_mfma_f32_32x32x16_bf16(eh1, xl[0][kt], a10, 0, 0, 0);
      a11 = __builtin_amdgcn_mfma_f32_32x32x16_bf16(eh1, xh[1][kt], a11, 0, 0, 0);
      a11 = __builtin_amdgcn_mfma_f32_32x32x16_bf16(el1, xh[1][kt], a11, 0, 0, 0);
      a11 = __builtin_amdgcn_mfma_f32_32x32x16_bf16(eh1, xl[1][kt], a11, 0, 0, 0);
    }
    {
      bf16x8 t30 = *(const bf16x8*)(cur + ((16 + 0) * 64 + lane) * 16);
      bf16x8 t31 = *(const bf16x8*)(cur + ((16 + 1) * 64 + lane) * 16);
      a00 = __builtin_amdgcn_mfma_f32_32x32x16_bf16(t30, bneg, a00, 0, 0, 0);
      a01 = __builtin_amdgcn_mfma_f32_32x32x16_bf16(t30, bneg, a01, 0, 0, 0);
      a10 = __builtin_amdgcn_mfma_f32_32x32x16_bf16(t31, bneg, a10, 0, 0, 0);
      a11 = __builtin_amdgcn_mfma_f32_32x32x16_bf16(t31, bneg, a11, 0, 0, 0);
    }

    float m0 = -3.4e38f, m1v = -3.4e38f;
#pragma unroll
    for (int e = 0; e < 16; ++e) {
      m0 = fmaxf(m0, fmaxf(a00[e], a10[e]));
      m1v = fmaxf(m1v, fmaxf(a01[e], a11[e]));
    }
    m0 = fmaxf(m0, __shfl_xor(m0, 32, 64));
    m1v = fmaxf(m1v, __shfl_xor(m1v, 32, 64));
    if (lane < 32) {
      size_t base = (size_t)(cs * 32 + it) * MROWS + row0;
      cm[base + nl] = m0;
      cm[base + 32 + nl] = m1v;
    }
    __syncthreads();
    b ^= 1;
  }
#undef STAGE
}

// Candidate select, tile form. Sub-bucketed counters: (ch, sub=bid&15) each
// on its own 64B cacheline -> ~67 atomics/line instead of 17K/line.
__global__ __launch_bounds__(256, 4)
void k_cand(const float* __restrict__ cm, int* __restrict__ cnt,
            int* __restrict__ pairs, unsigned long long* __restrict__ keys,
            float dlt) {
  __shared__ float wmax[4][64];
  __shared__ float thrs[64];
  const int tid = threadIdx.x, lane = tid & 63, w = tid >> 6;
  const int r = blockIdx.x * 64 + lane;
  const int sub = blockIdx.x & (NSUB - 1);
  float v[16];
#pragma unroll
  for (int i = 0; i < 16; ++i) v[i] = cm[(size_t)(w * 16 + i) * MROWS + r];
  float m = v[0];
#pragma unroll
  for (int i = 1; i < 16; ++i) m = fmaxf(m, v[i]);
  wmax[w][lane] = m;
  __syncthreads();
  if (w == 0) {
    float A = fmaxf(fmaxf(wmax[0][lane], wmax[1][lane]),
                    fmaxf(wmax[2][lane], wmax[3][lane]));
    thrs[lane] = A - dlt;
    keys[r] = ~0ull;
  }
  __syncthreads();
  float thr = thrs[lane];
#pragma unroll
  for (int i = 0; i < 16; ++i) {
    if (v[i] >= thr) {
      int ch = w * 16 + i;
      int slot = ch * NSUB + sub;
      int s = atomicAdd(cnt + slot * 16, 1);
      if (s < SUBCAP) pairs[slot * SUBCAP + s] = r;
    }
  }
}

// np-bit-exact rescore. Block = (chunk ch, sub-bucket): stages the chunk's
// 64 codes once in LDS, walks its own sub-list.
__global__ __launch_bounds__(256, 2)
void k_exact(const float* __restrict__ x, const float* __restrict__ cb,
             const int* __restrict__ cnt, const int* __restrict__ pairs,
             const float* __restrict__ t1, const float* __restrict__ t3,
             unsigned long long* __restrict__ keys) {
  __shared__ float elds[32 * 65 * 4];
  __shared__ float xlds[4][D_];
  int ch = blockIdx.x >> 4, sub = blockIdx.x & (NSUB - 1);
  int tid = threadIdx.x, lane = tid & 63, wid = tid >> 6;
#pragma unroll
  for (int it2 = 0; it2 < 8; ++it2) {
    int u = it2 * 256 + tid;        // 0..2047
    int c = u >> 5, d4 = u & 31;
    float4 v = *(const float4*)(cb + ((size_t)ch * 64 + c) * D_ + d4 * 4);
    *(float4*)(elds + (d4 * 65 + c) * 4) = v;
  }
  float t3v = t3[ch * 64 + lane];
  __syncthreads();
  int slot = ch * NSUB + sub;
  int n = cnt[slot * 16]; if (n > SUBCAP) n = SUBCAP;
  const int* lst = pairs + slot * SUBCAP;
  for (int idx = wid; idx < n; idx += 4) {
    int row = lst[idx];
    *(float2*)(&xlds[wid][lane * 2]) = *(const float2*)(x + (size_t)row * D_ + lane * 2);
    asm volatile("s_waitcnt lgkmcnt(0)" ::: "memory");
    float acc = 0.f;
    float t1r = t1[row];
#pragma unroll 8
    for (int d4 = 0; d4 < 32; ++d4) {
      float4 xv = *(const float4*)(&xlds[wid][d4 * 4]);
      float4 ev = *(const float4*)(elds + (d4 * 65 + lane) * 4);
      acc = __builtin_fmaf(xv.x, ev.x, acc);
      acc = __builtin_fmaf(xv.y, ev.y, acc);
      acc = __builtin_fmaf(xv.z, ev.z, acc);
      acc = __builtin_fmaf(xv.w, ev.w, acc);
    }
    float s = __builtin_fmaf(-2.f, acc, t1r) + t3v;
    unsigned u32 = __float_as_uint(s);
    u32 = u32 ^ (unsigned)(((int)u32 >> 31) | 0x80000000);
    unsigned long long key =
        ((unsigned long long)u32 << 12) | (unsigned)(ch * 64 + lane);
#pragma unroll
    for (int off = 1; off < 64; off <<= 1) {
      unsigned long long o = __shfl_xor(key, off, 64);
      key = o < key ? o : key;
    }
    if (lane == 0) atomicMin(keys + row, key);
  }
}

__global__ __launch_bounds__(256, 2)
void k_final(const unsigned long long* __restrict__ keys,
             float* __restrict__ tok_f, int* __restrict__ tok_i) {
  int r = blockIdx.x * 256 + threadIdx.x;
  int code = (int)(keys[r] & 0xFFFull);
  tok_f[r] = (float)code;
  tok_i[r] = code;
}

__global__ __launch_bounds__(256, 2)
void k_gather(const float* __restrict__ x, const float* __restrict__ cb,
              const int* __restrict__ tok_i, float* __restrict__ outq,
              float* __restrict__ partial) {
  int idx = blockIdx.x * 256 + threadIdx.x;
  int row = idx >> 5;
  int d4 = idx & 31;
  int t = tok_i[row];
  float4 q = ((const float4*)(cb + (size_t)t * D_))[d4];
  float4 xv = ((const float4*)x)[idx];
  ((float4*)outq)[idx] = q;
  float dx = q.x - xv.x, dy = q.y - xv.y, dz = q.z - xv.z, dw = q.w - xv.w;
  float s = dx * dx + dy * dy + dz * dz + dw * dw;
#pragma unroll
  for (int off = 1; off < 64; off <<= 1) s += __shfl_xor(s, off, 64);
  __shared__ float red[4];
  int lane = threadIdx.x & 63, w = threadIdx.x >> 6;
  if (lane == 0) red[w] = s;
  __syncthreads();
  if (threadIdx.x == 0)
    partial[blockIdx.x] = red[0] + red[1] + red[2] + red[3];
}

__global__ __launch_bounds__(256, 1)
void k_loss(const float* __restrict__ partial, int n, float* __restrict__ out_loss,
            float scale) {
  float s = 0.f;
  for (int i = threadIdx.x; i < n; i += 256) s += partial[i];
#pragma unroll
  for (int off = 1; off < 64; off <<= 1) s += __shfl_xor(s, off, 64);
  __shared__ float red[4];
  int lane = threadIdx.x & 63, w = threadIdx.x >> 6;
  if (lane == 0) red[w] = s;
  __syncthreads();
  if (threadIdx.x == 0)
    out_loss[0] = (red[0] + red[1] + red[2] + red[3]) * scale;
}

extern "C" void kernel_launch(void* const* d_in, const int* in_sizes, int n_in,
                              void* d_out, int out_size, void* d_ws, size_t ws_size,
                              hipStream_t stream) {
  const float* x = (const float*)d_in[0];
  const float* cb = (const float*)d_in[1];

  float* out_tok = (float*)d_out;
  float* outq = (float*)d_out + MROWS;
  float* out_loss = (float*)d_out + MROWS + (size_t)MROWS * D_;

  int* tok_i = (int*)d_ws;                          // 256 KB
  float* part = (float*)((char*)d_ws + 262144);     // 32 KB

  float* t3 = outq + OQ_T3;
  float* t1 = outq + OQ_T1;
  unsigned* t3hl = (unsigned*)(outq + OQ_T3HL);
  int* cnt = (int*)(outq + OQ_CNT);
  int* pairs = (int*)(outq + OQ_PAIRS);
  unsigned long long* keys = (unsigned long long*)(outq + OQ_KEYS);

  k_t3<<<KCODES / 256, 256, 0, stream>>>(cb, t3, t3hl);
  k_t1<<<MROWS / 256, 256, 0, stream>>>(x, t1);
  k_prep<<<(64 * 1152) / 256, 256, 0, stream>>>(cb, t3hl, outq);
  k_big<<<MROWS / 256, 512, 147456, stream>>>(x, outq);
  hipMemsetAsync(cnt, 0, 64 * NSUB * 16 * sizeof(int), stream);
  k_cand<<<MROWS / 64, 256, 0, stream>>>(outq, cnt, pairs, keys, 2e-3f);
  k_exact<<<64 * NSUB, 256, 0, stream>>>(x, cb, cnt, pairs, t1, t3, keys);
  k_final<<<MROWS / 256, 256, 0, stream>>>(keys, out_tok, tok_i);
  const int gB = (MROWS * (D_ / 4)) / 256;
  k_gather<<<gB, 256, 0, stream>>>(x, cb, tok_i, outq, part);
  k_loss<<<1, 256, 0, stream>>>(part, gB, out_loss,
                                1.5f / (float)((size_t)MROWS * D_));
}

// Round 8
// 260.218 us; speedup vs baseline: 4.6373x; 1.1421x over previous
//
#include <hip/hip_runtime.h>

// SharedVectorQuantizer forward, MI355X. x:[65536,128]f32 cb:[4096,128]f32
// out: tokens[M] (float) | quantized[M*128] | vq_loss[1]
//
// k_t3 (np ||e||^2), k_t1 (np ||x||^2), k_prep (codebook -> bf16 HI frags,
// fragment-linear), k_big (2-pass bf16-split MFMA approx xh*eh + xl*eh,
// t3/2 folded in epilogue from LDS; per (row, 64-code chunk) max), k_cand
// (chunks within dlt of row best -> sub-bucketed lists, padded counters),
// k_exact (np-bit-exact fp32 chain rescore, u64 atomicMin), k_final,
// k_gather, k_loss.  Approx error (dropped xh*el + xl*el) sigma ~2.5e-4
// in acc units; dlt = 6e-3 covers 2*max|eps| with >2x margin; exactness
// comes from the rescore, the filter only must contain the true chunk.
//
// Big scratch lives in the quantized-output region (dead before k_gather).

#define D_ 128
#define MROWS 65536
#define KCODES 4096
#define NSUB 16
#define SUBCAP 512

// float offsets within out_q scratch region (8388608 floats)
// cm occupies [0, 64*65536) = [0, 4194304)
#define OQ_AH    4194304   // 64 chunks * 1024 units * 16B bf16-hi frags
#define OQ_KEYS  4456448   // u64[65536]
#define OQ_PAIRS 4587520   // int[64*NSUB*SUBCAP] = 524288
#define OQ_T1    5111808   // f32[65536]
#define OQ_T3    5177344   // f32[4096]
#define OQ_CNT   5181440   // int[64*NSUB*16] (each counter on its own 64B line)

typedef __attribute__((ext_vector_type(8))) short bf16x8;
typedef __attribute__((ext_vector_type(16))) float f32x16;

__device__ __forceinline__ unsigned short bf16rne(float f) {
  unsigned u = __float_as_uint(f);
  unsigned r = (u + 0x7FFFu + ((u >> 16) & 1u)) >> 16;
  return (unsigned short)r;
}
__device__ __forceinline__ float bf16tof(unsigned short h) {
  return __uint_as_float(((unsigned)h) << 16);
}

__device__ __forceinline__ void gload_lds16(const void* g, void* l) {
  __builtin_amdgcn_global_load_lds(
      (const __attribute__((address_space(1))) unsigned int*)g,
      (__attribute__((address_space(3))) unsigned int*)l, 16, 0, 0);
}

__device__ __forceinline__ float4 f4add(float4 a, float4 b) {
  return make_float4(a.x + b.x, a.y + b.y, a.z + b.z, a.w + b.w);
}
__device__ __forceinline__ float4 f4sq(float4 v) {
  return make_float4(v.x * v.x, v.y * v.y, v.z * v.z, v.w * v.w);
}

// numpy fp32 pairwise sum of squares, AVX-512 npyv path (verified round 3)
__device__ __forceinline__ float np_sumsq_row(const float4* __restrict__ r) {
  float4 W[4];
#pragma unroll
  for (int a = 0; a < 4; ++a) {
    float4 c0 = f4sq(r[0 * 4 + a]), c1 = f4sq(r[1 * 4 + a]);
    float4 c2 = f4sq(r[2 * 4 + a]), c3 = f4sq(r[3 * 4 + a]);
    float4 c4 = f4sq(r[4 * 4 + a]), c5 = f4sq(r[5 * 4 + a]);
    float4 c6 = f4sq(r[6 * 4 + a]), c7 = f4sq(r[7 * 4 + a]);
    W[a] = f4add(f4add(f4add(c0, c1), f4add(c2, c3)),
                 f4add(f4add(c4, c5), f4add(c6, c7)));
  }
  float4 U0 = f4add(W[0], W[2]);
  float4 U1 = f4add(W[1], W[3]);
  float4 T = f4add(U0, U1);
  float s0 = T.x + T.z, s1 = T.y + T.w;
  return s0 + s1;
}

__global__ __launch_bounds__(256, 2)
void k_t3(const float* __restrict__ cb, float* __restrict__ t3) {
  int k = blockIdx.x * 256 + threadIdx.x;
  t3[k] = np_sumsq_row((const float4*)(cb + (size_t)k * D_));
}

__global__ __launch_bounds__(256, 2)
void k_t1(const float* __restrict__ x, float* __restrict__ t1) {
  int r = blockIdx.x * 256 + threadIdx.x;
  t1[r] = np_sumsq_row((const float4*)(x + (size_t)r * D_));
}

// codebook -> fragment-linear bf16 HI units. unit u in [0, 64*1024):
// ch=u>>10, s=(u&1023)>>6 (kt=s>>1, ct=s&1), p=u&63 (kg=p>>5, nl=p&31);
// code = ch*64 + ct*32 + nl, k-offset = (kt*2+kg)*8.
__global__ __launch_bounds__(256, 2)
void k_prep(const float* __restrict__ cb, float* __restrict__ outq) {
  int u = blockIdx.x * 256 + threadIdx.x;   // < 65536
  int ch = u >> 10, r = u & 1023;
  int s = r >> 6, p = r & 63;
  int kt = s >> 1, ct = s & 1;
  int kg = p >> 5, nl = p & 31;
  int code = ch * 64 + ct * 32 + nl;
  const float* src = cb + (size_t)code * D_ + (kt * 2 + kg) * 8;
  bf16x8 h;
#pragma unroll
  for (int e = 0; e < 8; ++e) h[e] = (short)bf16rne(src[e]);
  *(bf16x8*)((char*)(outq + OQ_AH) + (size_t)u * 16) = h;
}

// Approx sweep. 512 thr = 8 waves = 4 row-groups x 2 code-halves.
// Wave: 32 rows (x hi/lo frags in regs) x 64-code chunks (bf16-hi in LDS,
// dbuf). acc = xh*eh + xl*eh; cm[ch][row] = max over codes (acc - t3/2).
// LDS: 2 halves x 2 dbuf x 16KB + 16KB th = 80KB -> 2 blocks/CU.
__global__ __launch_bounds__(512, 4)
void k_big(const float* __restrict__ x, const float* __restrict__ t3,
           float* __restrict__ outq) {
  extern __shared__ char lds[];
  float* th_lds = (float*)(lds + 65536);
  const int tid = threadIdx.x;
  const int lane = tid & 63;
  const int wid = tid >> 6;
  const int rg = wid >> 1, cs = wid & 1;
  const int kg = lane >> 5, nl = lane & 31;
  const int row = blockIdx.x * 128 + rg * 32 + nl;

  const char* AhB = (const char*)(outq + OQ_AH);
  float* cm = outq;   // [64][65536]

  // x fragments: lane holds row `row`, k16 = kt*2+kg (matches B layout)
  bf16x8 xh[8], xl[8];
#pragma unroll
  for (int kt = 0; kt < 8; ++kt) {
    const float* src = x + (size_t)row * D_ + (kt * 2 + kg) * 8;
    float f[8];
    *(float4*)(f) = *(const float4*)(src);
    *(float4*)(f + 4) = *(const float4*)(src + 4);
    bf16x8 h, l;
#pragma unroll
    for (int e = 0; e < 8; ++e) {
      unsigned short hs = bf16rne(f[e]);
      h[e] = (short)hs;
      l[e] = (short)bf16rne(f[e] - bf16tof(hs));
    }
    xh[kt] = h;
    xl[kt] = l;
  }

  // th = 0.5 * ||e||^2, all 4096 codes, once per block
#pragma unroll
  for (int i = 0; i < 8; ++i) th_lds[tid + i * 512] = 0.5f * t3[tid + i * 512];

  char* half = lds + cs * 32768;

#define STAGE(c, buf)                                                         \
  {                                                                           \
    const char* sAh = AhB + (size_t)(c) * 16384;                              \
    _Pragma("unroll")                                                         \
    for (int it4 = 0; it4 < 4; ++it4) {                                       \
      int ub = it4 * 256 + rg * 64;                                           \
      gload_lds16(sAh + (size_t)(ub + lane) * 16, (buf) + ub * 16);           \
    }                                                                         \
  }

  STAGE(cs * 32 + 0, half + 0);
  __syncthreads();

  int b = 0;
  for (int it = 0; it < 32; ++it) {
    char* cur = half + b * 16384;
    if (it < 31) STAGE(cs * 32 + it + 1, half + (b ^ 1) * 16384);

    f32x16 a0 = 0, a1 = 0;   // ct = 0 / 1 code tiles
#pragma unroll
    for (int kt = 0; kt < 8; ++kt) {
      bf16x8 e0 = *(const bf16x8*)(cur + ((kt * 2 + 0) * 64 + lane) * 16);
      bf16x8 e1 = *(const bf16x8*)(cur + ((kt * 2 + 1) * 64 + lane) * 16);
      a0 = __builtin_amdgcn_mfma_f32_32x32x16_bf16(e0, xh[kt], a0, 0, 0, 0);
      a0 = __builtin_amdgcn_mfma_f32_32x32x16_bf16(e0, xl[kt], a0, 0, 0, 0);
      a1 = __builtin_amdgcn_mfma_f32_32x32x16_bf16(e1, xh[kt], a1, 0, 0, 0);
      a1 = __builtin_amdgcn_mfma_f32_32x32x16_bf16(e1, xl[kt], a1, 0, 0, 0);
    }

    // epilogue: max over 32 codes of (acc - th[code]); D rows = codes:
    // r = (e&3) + 8*(e>>2) + 4*(lane>>5); th reads are LDS broadcasts.
    int c0 = (cs * 32 + it) * 64;
    float m = -3.4e38f;
#pragma unroll
    for (int e = 0; e < 16; ++e) {
      int r = (e & 3) + 8 * (e >> 2) + 4 * kg;
      m = fmaxf(m, fmaxf(a0[e] - th_lds[c0 + r],
                         a1[e] - th_lds[c0 + 32 + r]));
    }
    m = fmaxf(m, __shfl_xor(m, 32, 64));
    if (lane < 32)
      cm[(size_t)(cs * 32 + it) * MROWS + blockIdx.x * 128 + rg * 32 + nl] = m;
    __syncthreads();
    b ^= 1;
  }
#undef STAGE
}

// Candidate select, tile form. Sub-bucketed counters: (ch, sub=bid&15) each
// on its own 64B cacheline -> no atomic contention (round 7 verified).
__global__ __launch_bounds__(256, 4)
void k_cand(const float* __restrict__ cm, int* __restrict__ cnt,
            int* __restrict__ pairs, unsigned long long* __restrict__ keys,
            float dlt) {
  __shared__ float wmax[4][64];
  __shared__ float thrs[64];
  const int tid = threadIdx.x, lane = tid & 63, w = tid >> 6;
  const int r = blockIdx.x * 64 + lane;
  const int sub = blockIdx.x & (NSUB - 1);
  float v[16];
#pragma unroll
  for (int i = 0; i < 16; ++i) v[i] = cm[(size_t)(w * 16 + i) * MROWS + r];
  float m = v[0];
#pragma unroll
  for (int i = 1; i < 16; ++i) m = fmaxf(m, v[i]);
  wmax[w][lane] = m;
  __syncthreads();
  if (w == 0) {
    float A = fmaxf(fmaxf(wmax[0][lane], wmax[1][lane]),
                    fmaxf(wmax[2][lane], wmax[3][lane]));
    thrs[lane] = A - dlt;
    keys[r] = ~0ull;
  }
  __syncthreads();
  float thr = thrs[lane];
#pragma unroll
  for (int i = 0; i < 16; ++i) {
    if (v[i] >= thr) {
      int ch = w * 16 + i;
      int slot = ch * NSUB + sub;
      int s = atomicAdd(cnt + slot * 16, 1);
      if (s < SUBCAP) pairs[slot * SUBCAP + s] = r;
    }
  }
}

// np-bit-exact rescore. Block = (chunk ch, sub-bucket): stages the chunk's
// 64 codes once in LDS, walks its own sub-list.
__global__ __launch_bounds__(256, 2)
void k_exact(const float* __restrict__ x, const float* __restrict__ cb,
             const int* __restrict__ cnt, const int* __restrict__ pairs,
             const float* __restrict__ t1, const float* __restrict__ t3,
             unsigned long long* __restrict__ keys) {
  __shared__ float elds[32 * 65 * 4];
  __shared__ float xlds[4][D_];
  int ch = blockIdx.x >> 4, sub = blockIdx.x & (NSUB - 1);
  int tid = threadIdx.x, lane = tid & 63, wid = tid >> 6;
#pragma unroll
  for (int it2 = 0; it2 < 8; ++it2) {
    int u = it2 * 256 + tid;        // 0..2047
    int c = u >> 5, d4 = u & 31;
    float4 v = *(const float4*)(cb + ((size_t)ch * 64 + c) * D_ + d4 * 4);
    *(float4*)(elds + (d4 * 65 + c) * 4) = v;
  }
  float t3v = t3[ch * 64 + lane];
  __syncthreads();
  int slot = ch * NSUB + sub;
  int n = cnt[slot * 16]; if (n > SUBCAP) n = SUBCAP;
  const int* lst = pairs + slot * SUBCAP;
  for (int idx = wid; idx < n; idx += 4) {
    int row = lst[idx];
    *(float2*)(&xlds[wid][lane * 2]) = *(const float2*)(x + (size_t)row * D_ + lane * 2);
    asm volatile("s_waitcnt lgkmcnt(0)" ::: "memory");
    float acc = 0.f;
    float t1r = t1[row];
#pragma unroll 8
    for (int d4 = 0; d4 < 32; ++d4) {
      float4 xv = *(const float4*)(&xlds[wid][d4 * 4]);
      float4 ev = *(const float4*)(elds + (d4 * 65 + lane) * 4);
      acc = __builtin_fmaf(xv.x, ev.x, acc);
      acc = __builtin_fmaf(xv.y, ev.y, acc);
      acc = __builtin_fmaf(xv.z, ev.z, acc);
      acc = __builtin_fmaf(xv.w, ev.w, acc);
    }
    float s = __builtin_fmaf(-2.f, acc, t1r) + t3v;
    unsigned u32 = __float_as_uint(s);
    u32 = u32 ^ (unsigned)(((int)u32 >> 31) | 0x80000000);
    unsigned long long key =
        ((unsigned long long)u32 << 12) | (unsigned)(ch * 64 + lane);
#pragma unroll
    for (int off = 1; off < 64; off <<= 1) {
      unsigned long long o = __shfl_xor(key, off, 64);
      key = o < key ? o : key;
    }
    if (lane == 0) atomicMin(keys + row, key);
  }
}

__global__ __launch_bounds__(256, 2)
void k_final(const unsigned long long* __restrict__ keys,
             float* __restrict__ tok_f, int* __restrict__ tok_i) {
  int r = blockIdx.x * 256 + threadIdx.x;
  int code = (int)(keys[r] & 0xFFFull);
  tok_f[r] = (float)code;
  tok_i[r] = code;
}

__global__ __launch_bounds__(256, 2)
void k_gather(const float* __restrict__ x, const float* __restrict__ cb,
              const int* __restrict__ tok_i, float* __restrict__ outq,
              float* __restrict__ partial) {
  int idx = blockIdx.x * 256 + threadIdx.x;
  int row = idx >> 5;
  int d4 = idx & 31;
  int t = tok_i[row];
  float4 q = ((const float4*)(cb + (size_t)t * D_))[d4];
  float4 xv = ((const float4*)x)[idx];
  ((float4*)outq)[idx] = q;
  float dx = q.x - xv.x, dy = q.y - xv.y, dz = q.z - xv.z, dw = q.w - xv.w;
  float s = dx * dx + dy * dy + dz * dz + dw * dw;
#pragma unroll
  for (int off = 1; off < 64; off <<= 1) s += __shfl_xor(s, off, 64);
  __shared__ float red[4];
  int lane = threadIdx.x & 63, w = threadIdx.x >> 6;
  if (lane == 0) red[w] = s;
  __syncthreads();
  if (threadIdx.x == 0)
    partial[blockIdx.x] = red[0] + red[1] + red[2] + red[3];
}

__global__ __launch_bounds__(256, 1)
void k_loss(const float* __restrict__ partial, int n, float* __restrict__ out_loss,
            float scale) {
  float s = 0.f;
  for (int i = threadIdx.x; i < n; i += 256) s += partial[i];
#pragma unroll
  for (int off = 1; off < 64; off <<= 1) s += __shfl_xor(s, off, 64);
  __shared__ float red[4];
  int lane = threadIdx.x & 63, w = threadIdx.x >> 6;
  if (lane == 0) red[w] = s;
  __syncthreads();
  if (threadIdx.x == 0)
    out_loss[0] = (red[0] + red[1] + red[2] + red[3]) * scale;
}

extern "C" void kernel_launch(void* const* d_in, const int* in_sizes, int n_in,
                              void* d_out, int out_size, void* d_ws, size_t ws_size,
                              hipStream_t stream) {
  const float* x = (const float*)d_in[0];
  const float* cb = (const float*)d_in[1];

  float* out_tok = (float*)d_out;
  float* outq = (float*)d_out + MROWS;
  float* out_loss = (float*)d_out + MROWS + (size_t)MROWS * D_;

  int* tok_i = (int*)d_ws;                          // 256 KB
  float* part = (float*)((char*)d_ws + 262144);     // 32 KB

  float* t3 = outq + OQ_T3;
  float* t1 = outq + OQ_T1;
  int* cnt = (int*)(outq + OQ_CNT);
  int* pairs = (int*)(outq + OQ_PAIRS);
  unsigned long long* keys = (unsigned long long*)(outq + OQ_KEYS);

  k_t3<<<KCODES / 256, 256, 0, stream>>>(cb, t3);
  k_t1<<<MROWS / 256, 256, 0, stream>>>(x, t1);
  k_prep<<<(64 * 1024) / 256, 256, 0, stream>>>(cb, outq);
  k_big<<<MROWS / 128, 512, 81920, stream>>>(x, t3, outq);
  hipMemsetAsync(cnt, 0, 64 * NSUB * 16 * sizeof(int), stream);
  k_cand<<<MROWS / 64, 256, 0, stream>>>(outq, cnt, pairs, keys, 6e-3f);
  k_exact<<<64 * NSUB, 256, 0, stream>>>(x, cb, cnt, pairs, t1, t3, keys);
  k_final<<<MROWS / 256, 256, 0, stream>>>(keys, out_tok, tok_i);
  const int gB = (MROWS * (D_ / 4)) / 256;
  k_gather<<<gB, 256, 0, stream>>>(x, cb, tok_i, outq, part);
  k_loss<<<1, 256, 0, stream>>>(part, gB, out_loss,
                                1.5f / (float)((size_t)MROWS * D_));
}

// Round 11
// 195.389 us; speedup vs baseline: 6.1759x; 1.3318x over previous
//
#include <hip/hip_runtime.h>

// SharedVectorQuantizer forward, MI355X. x:[65536,128]f32 cb:[4096,128]f32
// out: tokens[M] (float) | quantized[M*128] | vq_loss[1]
//
// k_pre   : fused np ||x||^2, np ||e||^2 (+ bf16 hi/lo pack), codebook->
//           bf16-hi fragment prep, candidate-counter zeroing.
// k_big   : 1-pass bf16-hi MFMA filter, xt=2 (64 rows/wave), -t3/2 folded
//           via t3hl MFMA slab (bneg trick, verified round 7).
//           cm[ch][row] = max over chunk codes of (acc - t3/2).
// k_cand  : chunks within dlt of row best -> sub-bucketed lists (padded
//           counters, no atomic contention). dlt = 8e-3 (~11 sigma of the
//           1-pass filter error; exactness from the rescore).
// k_exact : np-bit-exact fp32 chain rescore of candidates, u64 atomicMin.
// k_final : keys -> tokens + tok_i (in d_ws). MUST run before k_gather:
//           k_gather overwrites the whole quantized region, which hosts
//           the keys scratch (round-9/10 bug: folding this caused a race).
// k_gather: gather quantized rows from tok_i, partial MSE.
// k_loss  : reduce -> 1.5 * mean.
//
// Big scratch lives in the quantized-output region (dead before k_gather).

#define D_ 128
#define MROWS 65536
#define KCODES 4096
#define NSUB 16
#define SUBCAP 512

// float offsets within out_q scratch region (8388608 floats)
// cm occupies [0, 64*65536) = [0, 4194304)
#define OQ_AH    4194304   // 64 chunks * 1024 units * 16B bf16-hi frags
#define OQ_KEYS  4456448   // u64[65536]
#define OQ_PAIRS 4587520   // int[64*NSUB*SUBCAP] = 524288
#define OQ_T1    5111808   // f32[65536]
#define OQ_T3    5177344   // f32[4096]
#define OQ_CNT   5181440   // int[64*NSUB*16] (each counter on its own 64B line)
#define OQ_T3HL  5197824   // u32[4096] packed t3h | t3l<<16

typedef __attribute__((ext_vector_type(8))) short bf16x8;
typedef __attribute__((ext_vector_type(16))) float f32x16;

__device__ __forceinline__ unsigned short bf16rne(float f) {
  unsigned u = __float_as_uint(f);
  unsigned r = (u + 0x7FFFu + ((u >> 16) & 1u)) >> 16;
  return (unsigned short)r;
}
__device__ __forceinline__ float bf16tof(unsigned short h) {
  return __uint_as_float(((unsigned)h) << 16);
}

__device__ __forceinline__ void gload_lds16(const void* g, void* l) {
  __builtin_amdgcn_global_load_lds(
      (const __attribute__((address_space(1))) unsigned int*)g,
      (__attribute__((address_space(3))) unsigned int*)l, 16, 0, 0);
}

__device__ __forceinline__ float4 f4add(float4 a, float4 b) {
  return make_float4(a.x + b.x, a.y + b.y, a.z + b.z, a.w + b.w);
}
__device__ __forceinline__ float4 f4sq(float4 v) {
  return make_float4(v.x * v.x, v.y * v.y, v.z * v.z, v.w * v.w);
}

// numpy fp32 pairwise sum of squares, AVX-512 npyv path (verified round 3)
__device__ __forceinline__ float np_sumsq_row(const float4* __restrict__ r) {
  float4 W[4];
#pragma unroll
  for (int a = 0; a < 4; ++a) {
    float4 c0 = f4sq(r[0 * 4 + a]), c1 = f4sq(r[1 * 4 + a]);
    float4 c2 = f4sq(r[2 * 4 + a]), c3 = f4sq(r[3 * 4 + a]);
    float4 c4 = f4sq(r[4 * 4 + a]), c5 = f4sq(r[5 * 4 + a]);
    float4 c6 = f4sq(r[6 * 4 + a]), c7 = f4sq(r[7 * 4 + a]);
    W[a] = f4add(f4add(f4add(c0, c1), f4add(c2, c3)),
                 f4add(f4add(c4, c5), f4add(c6, c7)));
  }
  float4 U0 = f4add(W[0], W[2]);
  float4 U1 = f4add(W[1], W[3]);
  float4 T = f4add(U0, U1);
  float s0 = T.x + T.z, s1 = T.y + T.w;
  return s0 + s1;
}

// Fused prologue: t1 all rows, t3/t3hl first 4096 ids, counter zero first
// 16384 ids, prep unit per id. Grid 256 x 256 = 65536 threads.
__global__ __launch_bounds__(256, 2)
void k_pre(const float* __restrict__ x, const float* __restrict__ cb,
           float* __restrict__ outq) {
  int gid = blockIdx.x * 256 + threadIdx.x;
  float* t1 = outq + OQ_T1;
  float* t3 = outq + OQ_T3;
  unsigned* t3hl = (unsigned*)(outq + OQ_T3HL);
  int* cnt = (int*)(outq + OQ_CNT);

  t1[gid] = np_sumsq_row((const float4*)(x + (size_t)gid * D_));
  if (gid < KCODES) {
    float s = np_sumsq_row((const float4*)(cb + (size_t)gid * D_));
    t3[gid] = s;
    unsigned short h = bf16rne(s);
    unsigned short l = bf16rne(s - bf16tof(h));
    t3hl[gid] = (unsigned)h | ((unsigned)l << 16);
  }
  if (gid < 64 * NSUB * 16) cnt[gid] = 0;

  // prep unit u: ch=u>>10, s=(u&1023)>>6 (kt=s>>1, ct=s&1), p=u&63
  // (kg=p>>5, nl=p&31); code = ch*64+ct*32+nl, k-off = (kt*2+kg)*8.
  int u = gid;
  int ch = u >> 10, r = u & 1023;
  int s2 = r >> 6, p = r & 63;
  int kt = s2 >> 1, ct = s2 & 1;
  int kg = p >> 5, nl = p & 31;
  int code = ch * 64 + ct * 32 + nl;
  const float* src = cb + (size_t)code * D_ + (kt * 2 + kg) * 8;
  bf16x8 h8;
#pragma unroll
  for (int e = 0; e < 8; ++e) h8[e] = (short)bf16rne(src[e]);
  *(bf16x8*)((char*)(outq + OQ_AH) + (size_t)u * 16) = h8;
}

// Filter sweep. Block = 256 thr = 4 waves; wave = 64 rows (xt=2) x 64-code
// chunks. Grid = 256 row-groups x 4 chunk-splits (16 chunks each).
// acc = xh*eh - t3/2 (t3 slab via bneg MFMA, frags from 2 global dwords).
// Per iter: 16 ds_read_b128 feed 32 MFMA (4 per read) + 4 slab MFMA.
__global__ __launch_bounds__(256, 3)
void k_big(const float* __restrict__ x, const unsigned* __restrict__ t3hl,
           float* __restrict__ outq) {
  __shared__ char lds[2][16384];
  const int tid = threadIdx.x;
  const int lane = tid & 63;
  const int w = tid >> 6;
  const int kg = lane >> 5, nl = lane & 31;
  const int rb = blockIdx.x >> 2, cs = blockIdx.x & 3;
  const int row0 = rb * 256 + w * 64;

  const char* AhB = (const char*)(outq + OQ_AH);
  float* cm = outq;   // [64][65536]

  // x-hi fragments: lane holds row row0+xt*32+nl, k = (kt*2+kg)*8 + e
  bf16x8 xh[2][8];
#pragma unroll
  for (int xt = 0; xt < 2; ++xt)
#pragma unroll
    for (int kt = 0; kt < 8; ++kt) {
      const float* src =
          x + (size_t)(row0 + xt * 32 + nl) * D_ + (kt * 2 + kg) * 8;
      float f[8];
      *(float4*)(f) = *(const float4*)(src);
      *(float4*)(f + 4) = *(const float4*)(src + 4);
      bf16x8 h;
#pragma unroll
      for (int e = 0; e < 8; ++e) h[e] = (short)bf16rne(f[e]);
      xh[xt][kt] = h;
    }

  // B frag for t3 slab: k=0,1 hold -0.5 (kg==0 lanes)
  bf16x8 bneg = 0;
  if (kg == 0) { bneg[0] = (short)0xBF00; bneg[1] = (short)0xBF00; }

#define STAGE(c, buf)                                                         \
  {                                                                           \
    const char* sAh = AhB + (size_t)(c) * 16384;                              \
    _Pragma("unroll")                                                         \
    for (int i4 = 0; i4 < 4; ++i4) {                                          \
      int ub = i4 * 256 + w * 64;                                             \
      gload_lds16(sAh + (size_t)(ub + lane) * 16, (buf) + ub * 16);           \
    }                                                                         \
  }

  STAGE(cs * 16 + 0, lds[0]);
  __syncthreads();

  int b = 0;
  for (int it = 0; it < 16; ++it) {
    int ch = cs * 16 + it;
    char* cur = lds[b];
    if (it < 15) STAGE(ch + 1, lds[b ^ 1]);

    // t3 slab A-frags: lane row = code (nl), kg0 k0/k1 = t3h/t3l
    unsigned v0 = t3hl[ch * 64 + nl];
    unsigned v1 = t3hl[ch * 64 + 32 + nl];
    bf16x8 s0 = 0, s1 = 0;
    if (kg == 0) {
      s0[0] = (short)(v0 & 0xFFFFu); s0[1] = (short)(v0 >> 16);
      s1[0] = (short)(v1 & 0xFFFFu); s1[1] = (short)(v1 >> 16);
    }

    // acc[ct][xt]: D rows = codes (ct tile), cols = x-rows (xt tile)
    f32x16 a00 = 0, a01 = 0, a10 = 0, a11 = 0;
    a00 = __builtin_amdgcn_mfma_f32_32x32x16_bf16(s0, bneg, a00, 0, 0, 0);
    a01 = __builtin_amdgcn_mfma_f32_32x32x16_bf16(s0, bneg, a01, 0, 0, 0);
    a10 = __builtin_amdgcn_mfma_f32_32x32x16_bf16(s1, bneg, a10, 0, 0, 0);
    a11 = __builtin_amdgcn_mfma_f32_32x32x16_bf16(s1, bneg, a11, 0, 0, 0);
#pragma unroll
    for (int kt = 0; kt < 8; ++kt) {
      bf16x8 e0 = *(const bf16x8*)(cur + ((kt * 2 + 0) * 64 + lane) * 16);
      bf16x8 e1 = *(const bf16x8*)(cur + ((kt * 2 + 1) * 64 + lane) * 16);
      a00 = __builtin_amdgcn_mfma_f32_32x32x16_bf16(e0, xh[0][kt], a00, 0, 0, 0);
      a01 = __builtin_amdgcn_mfma_f32_32x32x16_bf16(e0, xh[1][kt], a01, 0, 0, 0);
      a10 = __builtin_amdgcn_mfma_f32_32x32x16_bf16(e1, xh[0][kt], a10, 0, 0, 0);
      a11 = __builtin_amdgcn_mfma_f32_32x32x16_bf16(e1, xh[1][kt], a11, 0, 0, 0);
    }

    // per-row chunk max over both ct tiles, then across kg halves
    float m0 = -3.4e38f, m1 = -3.4e38f;
#pragma unroll
    for (int e = 0; e < 16; ++e) {
      m0 = fmaxf(m0, fmaxf(a00[e], a10[e]));   // xt0 rows
      m1 = fmaxf(m1, fmaxf(a01[e], a11[e]));   // xt1 rows
    }
    m0 = fmaxf(m0, __shfl_xor(m0, 32, 64));
    m1 = fmaxf(m1, __shfl_xor(m1, 32, 64));
    float mv = (kg == 0) ? m0 : m1;            // lanes 0-31: xt0, 32-63: xt1
    cm[(size_t)ch * MROWS + row0 + kg * 32 + nl] = mv;
    __syncthreads();
    b ^= 1;
  }
#undef STAGE
}

// Candidate select, tile form. Sub-bucketed counters: (ch, sub=bid&15) each
// on its own 64B cacheline -> no atomic contention (round 7 verified).
__global__ __launch_bounds__(256, 4)
void k_cand(const float* __restrict__ cm, int* __restrict__ cnt,
            int* __restrict__ pairs, unsigned long long* __restrict__ keys,
            float dlt) {
  __shared__ float wmax[4][64];
  __shared__ float thrs[64];
  const int tid = threadIdx.x, lane = tid & 63, w = tid >> 6;
  const int r = blockIdx.x * 64 + lane;
  const int sub = blockIdx.x & (NSUB - 1);
  float v[16];
#pragma unroll
  for (int i = 0; i < 16; ++i) v[i] = cm[(size_t)(w * 16 + i) * MROWS + r];
  float m = v[0];
#pragma unroll
  for (int i = 1; i < 16; ++i) m = fmaxf(m, v[i]);
  wmax[w][lane] = m;
  __syncthreads();
  if (w == 0) {
    float A = fmaxf(fmaxf(wmax[0][lane], wmax[1][lane]),
                    fmaxf(wmax[2][lane], wmax[3][lane]));
    thrs[lane] = A - dlt;
    keys[r] = ~0ull;
  }
  __syncthreads();
  float thr = thrs[lane];
#pragma unroll
  for (int i = 0; i < 16; ++i) {
    if (v[i] >= thr) {
      int ch = w * 16 + i;
      int slot = ch * NSUB + sub;
      int s = atomicAdd(cnt + slot * 16, 1);
      if (s < SUBCAP) pairs[slot * SUBCAP + s] = r;
    }
  }
}

// np-bit-exact rescore. Block = (chunk ch, sub-bucket): stages the chunk's
// 64 codes once in LDS, walks its own sub-list.
__global__ __launch_bounds__(256, 2)
void k_exact(const float* __restrict__ x, const float* __restrict__ cb,
             const int* __restrict__ cnt, const int* __restrict__ pairs,
             const float* __restrict__ t1, const float* __restrict__ t3,
             unsigned long long* __restrict__ keys) {
  __shared__ float elds[32 * 65 * 4];
  __shared__ float xlds[4][D_];
  int ch = blockIdx.x >> 4, sub = blockIdx.x & (NSUB - 1);
  int tid = threadIdx.x, lane = tid & 63, wid = tid >> 6;
#pragma unroll
  for (int it2 = 0; it2 < 8; ++it2) {
    int u = it2 * 256 + tid;        // 0..2047
    int c = u >> 5, d4 = u & 31;
    float4 v = *(const float4*)(cb + ((size_t)ch * 64 + c) * D_ + d4 * 4);
    *(float4*)(elds + (d4 * 65 + c) * 4) = v;
  }
  float t3v = t3[ch * 64 + lane];
  __syncthreads();
  int slot = ch * NSUB + sub;
  int n = cnt[slot * 16]; if (n > SUBCAP) n = SUBCAP;
  const int* lst = pairs + slot * SUBCAP;
  for (int idx = wid; idx < n; idx += 4) {
    int row = lst[idx];
    *(float2*)(&xlds[wid][lane * 2]) = *(const float2*)(x + (size_t)row * D_ + lane * 2);
    asm volatile("s_waitcnt lgkmcnt(0)" ::: "memory");
    float acc = 0.f;
    float t1r = t1[row];
#pragma unroll 8
    for (int d4 = 0; d4 < 32; ++d4) {
      float4 xv = *(const float4*)(&xlds[wid][d4 * 4]);
      float4 ev = *(const float4*)(elds + (d4 * 65 + lane) * 4);
      acc = __builtin_fmaf(xv.x, ev.x, acc);
      acc = __builtin_fmaf(xv.y, ev.y, acc);
      acc = __builtin_fmaf(xv.z, ev.z, acc);
      acc = __builtin_fmaf(xv.w, ev.w, acc);
    }
    float s = __builtin_fmaf(-2.f, acc, t1r) + t3v;
    unsigned u32 = __float_as_uint(s);
    u32 = u32 ^ (unsigned)(((int)u32 >> 31) | 0x80000000);
    unsigned long long key =
        ((unsigned long long)u32 << 12) | (unsigned)(ch * 64 + lane);
#pragma unroll
    for (int off = 1; off < 64; off <<= 1) {
      unsigned long long o = __shfl_xor(key, off, 64);
      key = o < key ? o : key;
    }
    if (lane == 0) atomicMin(keys + row, key);
  }
}

// keys -> tokens + tok_i (tok_i lives in d_ws; must complete before
// k_gather overwrites the quantized region that hosts keys).
__global__ __launch_bounds__(256, 2)
void k_final(const unsigned long long* __restrict__ keys,
             float* __restrict__ tok_f, int* __restrict__ tok_i) {
  int r = blockIdx.x * 256 + threadIdx.x;
  int code = (int)(keys[r] & 0xFFFull);
  tok_f[r] = (float)code;
  tok_i[r] = code;
}

__global__ __launch_bounds__(256, 2)
void k_gather(const float* __restrict__ x, const float* __restrict__ cb,
              const int* __restrict__ tok_i, float* __restrict__ outq,
              float* __restrict__ partial) {
  int idx = blockIdx.x * 256 + threadIdx.x;
  int row = idx >> 5;
  int d4 = idx & 31;
  int t = tok_i[row];
  float4 q = ((const float4*)(cb + (size_t)t * D_))[d4];
  float4 xv = ((const float4*)x)[idx];
  ((float4*)outq)[idx] = q;
  float dx = q.x - xv.x, dy = q.y - xv.y, dz = q.z - xv.z, dw = q.w - xv.w;
  float s = dx * dx + dy * dy + dz * dz + dw * dw;
#pragma unroll
  for (int off = 1; off < 64; off <<= 1) s += __shfl_xor(s, off, 64);
  __shared__ float red[4];
  int lane = threadIdx.x & 63, w = threadIdx.x >> 6;
  if (lane == 0) red[w] = s;
  __syncthreads();
  if (threadIdx.x == 0)
    partial[blockIdx.x] = red[0] + red[1] + red[2] + red[3];
}

__global__ __launch_bounds__(256, 1)
void k_loss(const float* __restrict__ partial, int n, float* __restrict__ out_loss,
            float scale) {
  float s = 0.f;
  for (int i = threadIdx.x; i < n; i += 256) s += partial[i];
#pragma unroll
  for (int off = 1; off < 64; off <<= 1) s += __shfl_xor(s, off, 64);
  __shared__ float red[4];
  int lane = threadIdx.x & 63, w = threadIdx.x >> 6;
  if (lane == 0) red[w] = s;
  __syncthreads();
  if (threadIdx.x == 0)
    out_loss[0] = (red[0] + red[1] + red[2] + red[3]) * scale;
}

extern "C" void kernel_launch(void* const* d_in, const int* in_sizes, int n_in,
                              void* d_out, int out_size, void* d_ws, size_t ws_size,
                              hipStream_t stream) {
  const float* x = (const float*)d_in[0];
  const float* cb = (const float*)d_in[1];

  float* out_tok = (float*)d_out;
  float* outq = (float*)d_out + MROWS;
  float* out_loss = (float*)d_out + MROWS + (size_t)MROWS * D_;

  int* tok_i = (int*)d_ws;                          // 256 KB (proven in r4-8)
  float* part = (float*)((char*)d_ws + 262144);     // 32 KB

  float* t3 = outq + OQ_T3;
  float* t1 = outq + OQ_T1;
  unsigned* t3hl = (unsigned*)(outq + OQ_T3HL);
  int* cnt = (int*)(outq + OQ_CNT);
  int* pairs = (int*)(outq + OQ_PAIRS);
  unsigned long long* keys = (unsigned long long*)(outq + OQ_KEYS);

  k_pre<<<MROWS / 256, 256, 0, stream>>>(x, cb, outq);
  k_big<<<(MROWS / 256) * 4, 256, 0, stream>>>(x, t3hl, outq);
  k_cand<<<MROWS / 64, 256, 0, stream>>>(outq, cnt, pairs, keys, 8e-3f);
  k_exact<<<64 * NSUB, 256, 0, stream>>>(x, cb, cnt, pairs, t1, t3, keys);
  k_final<<<MROWS / 256, 256, 0, stream>>>(keys, out_tok, tok_i);
  const int gB = (MROWS * (D_ / 4)) / 256;
  k_gather<<<gB, 256, 0, stream>>>(x, cb, tok_i, outq, part);
  k_loss<<<1, 256, 0, stream>>>(part, gB, out_loss,
                                1.5f / (float)((size_t)MROWS * D_));
}